// Round 1
// baseline (3270.440 us; speedup 1.0000x reference)
//
#include <hip/hip_runtime.h>
#include <math.h>

#define D_MODEL 768
#define D_INNER 1536
#define B_SZ 4
#define T_SZ 512
#define ROWS (B_SZ*T_SZ)   // 2048
#define XP_N 80

__device__ __forceinline__ float sigmoidf_(float x){ return 1.0f/(1.0f+__expf(-x)); }
__device__ __forceinline__ float siluf_(float x){ return x*sigmoidf_(x); }

// ---------------- transpose: x (B,256,512) -> xt (B,512,256) ----------------
__global__ void transpose_x(const float* __restrict__ x, float* __restrict__ xt){
  __shared__ float s[32][33];
  int b = blockIdx.z;
  int t0 = blockIdx.x*32, c0 = blockIdx.y*32;
  int tx = threadIdx.x, ty = threadIdx.y;
  s[ty][tx] = x[((size_t)b*256 + (c0+ty))*512 + (t0+tx)];
  __syncthreads();
  xt[((size_t)b*512 + (t0+ty))*256 + (c0+tx)] = s[tx][ty];
}

// ---------------- SGEMM: C[M,N] = A[M,K] (row-major, stride lda) * W[N,K]^T + bias ----------------
// act: 0 = none, 1 = softplus
__global__ __launch_bounds__(256) void sgemm_tn(
    const float* __restrict__ A, int lda,
    const float* __restrict__ W,
    const float* __restrict__ bias,
    float* __restrict__ C, int M, int N, int K, int act)
{
  __shared__ float As[16][64];
  __shared__ float Ws[16][64];
  const int bm = blockIdx.y*64, bn = blockIdx.x*64;
  const int tid = threadIdx.x;
  const int tx = tid & 15, ty = tid >> 4;
  const int lm = tid & 63, lk = (tid >> 6) << 2;
  float acc[4][4] = {};
  const float* Ap = A + (size_t)(bm+lm)*lda + lk;
  const float* Wp = W + (size_t)(bn+lm)*K + lk;
  const bool wok = (bn+lm) < N;
  for (int k0 = 0; k0 < K; k0 += 16){
    float4 av = *(const float4*)(Ap + k0);
    float4 wv = wok ? *(const float4*)(Wp + k0) : make_float4(0.f,0.f,0.f,0.f);
    As[lk+0][lm]=av.x; As[lk+1][lm]=av.y; As[lk+2][lm]=av.z; As[lk+3][lm]=av.w;
    Ws[lk+0][lm]=wv.x; Ws[lk+1][lm]=wv.y; Ws[lk+2][lm]=wv.z; Ws[lk+3][lm]=wv.w;
    __syncthreads();
    #pragma unroll
    for (int k = 0; k < 16; k++){
      float a[4], w[4];
      #pragma unroll
      for (int i=0;i<4;i++) a[i] = As[k][ty*4+i];
      #pragma unroll
      for (int j=0;j<4;j++) w[j] = Ws[k][tx*4+j];
      #pragma unroll
      for (int i=0;i<4;i++)
        #pragma unroll
        for (int j=0;j<4;j++)
          acc[i][j] += a[i]*w[j];
    }
    __syncthreads();
  }
  #pragma unroll
  for (int i=0;i<4;i++){
    const int r = bm + ty*4 + i;
    #pragma unroll
    for (int j=0;j<4;j++){
      const int n = bn + tx*4 + j;
      if (n < N){
        float v = acc[i][j] + (bias ? bias[n] : 0.f);
        if (act == 1){ v = (v > 20.f) ? v : log1pf(__expf(v)); }
        C[(size_t)r*N + n] = v;
      }
    }
  }
}

// ---------------- residual add + RMSNorm ----------------
// resid (2048,768) updated in place if add != null; out = rmsnorm(resid)*w
__global__ __launch_bounds__(256) void add_rmsnorm(
    float* __restrict__ resid, const float* __restrict__ add,
    const float* __restrict__ w, float* __restrict__ out)
{
  const int row = blockIdx.x;
  const int tid = threadIdx.x;
  float v[3];
  float ss = 0.f;
  #pragma unroll
  for (int i=0;i<3;i++){
    const int c = tid + i*256;
    float r = resid[(size_t)row*768 + c];
    if (add) r += add[(size_t)row*768 + c];
    v[i] = r;
    ss += r*r;
  }
  #pragma unroll
  for (int off=32; off>=1; off>>=1) ss += __shfl_xor(ss, off);
  __shared__ float sred[4];
  const int lane = tid & 63, wv = tid >> 6;
  if (lane == 0) sred[wv] = ss;
  __syncthreads();
  const float tot = sred[0]+sred[1]+sred[2]+sred[3];
  const float scale = rsqrtf(tot*(1.0f/768.0f) + 1e-5f);
  #pragma unroll
  for (int i=0;i<3;i++){
    const int c = tid + i*256;
    if (add) resid[(size_t)row*768 + c] = v[i];
    out[(size_t)row*768 + c] = v[i]*scale*w[c];
  }
}

// ---------------- causal depthwise conv (K=4) + silu ----------------
// u = xz[:, :1536] per row; out uo (2048,1536)
__global__ __launch_bounds__(256) void conv_silu(
    const float* __restrict__ xz, const float* __restrict__ cw,
    const float* __restrict__ cb, float* __restrict__ uo)
{
  const int idx = blockIdx.x*256 + threadIdx.x;
  if (idx >= ROWS*D_INNER) return;
  const int d = idx % D_INNER;
  const int row = idx / D_INNER;
  const int t = row & (T_SZ-1);
  float acc = cb[d];
  #pragma unroll
  for (int k=0;k<4;k++){
    const int tt = t - 3 + k;
    if (tt >= 0)
      acc += xz[(size_t)(row - 3 + k)*3072 + d] * cw[d*4 + k];
  }
  uo[idx] = siluf_(acc);
}

// ---------------- fused selective scan ----------------
// lane = (d-sub, n): 16 d per block x 16 n. y written to yb (may alias delta).
__global__ __launch_bounds__(256) void mamba_scan(
    const float* delta, const float* __restrict__ u,
    const float* __restrict__ xp, const float* __restrict__ xz,
    const float* __restrict__ alog, const float* __restrict__ Dp,
    float* yb)
{
  const int tid = threadIdx.x;
  const int n = tid & 15;
  const int d = blockIdx.x*16 + (tid >> 4);
  const int b = blockIdx.y;
  const float Av = -__expf(alog[d*16 + n]);
  const float Dv = Dp[d];
  float h = 0.f;
  const size_t base = (size_t)b*T_SZ;
  for (int t=0; t<T_SZ; t++){
    const size_t row = base + t;
    const float dv = delta[row*D_INNER + d];
    const float uv = u[row*D_INNER + d];
    const float Bv = xp[row*XP_N + 48 + n];
    const float Cv = xp[row*XP_N + 64 + n];
    const float dA = __expf(dv * Av);
    h = dA*h + (dv*uv)*Bv;
    float p = h*Cv;
    p += __shfl_xor(p, 1);
    p += __shfl_xor(p, 2);
    p += __shfl_xor(p, 4);
    p += __shfl_xor(p, 8);
    if (n == 0){
      const float zv = xz[row*3072 + 1536 + d];
      yb[row*D_INNER + d] = (p + uv*Dv) * siluf_(zv);
    }
  }
}

// ---------------- mean pool over T ----------------
__global__ void pool_mean(const float* __restrict__ normed, float* __restrict__ pooled){
  const int idx = blockIdx.x*256 + threadIdx.x;
  if (idx >= B_SZ*768) return;
  const int b = idx / 768, m = idx % 768;
  float s = 0.f;
  for (int t=0; t<T_SZ; t++) s += normed[((size_t)b*T_SZ + t)*768 + m];
  pooled[idx] = s * (1.0f/T_SZ);
}

// ---------------- classifier head: out (4,10) ----------------
__global__ void cls_head(const float* __restrict__ pooled, const float* __restrict__ cw,
                         const float* __restrict__ cb, float* __restrict__ out){
  const int o = blockIdx.x % 10, b = blockIdx.x / 10;
  const int lane = threadIdx.x; // 64
  float s = 0.f;
  for (int k = lane; k < 768; k += 64) s += pooled[b*768 + k]*cw[o*768 + k];
  #pragma unroll
  for (int off=32; off>=1; off>>=1) s += __shfl_xor(s, off);
  if (lane == 0) out[b*10 + o] = s + cb[o];
}

extern "C" void kernel_launch(void* const* d_in, const int* in_sizes, int n_in,
                              void* d_out, int out_size, void* d_ws, size_t ws_size,
                              hipStream_t stream) {
  const float* x         = (const float*)d_in[0];
  const float* in_proj_w = (const float*)d_in[1];
  const float* conv_w    = (const float*)d_in[2];
  const float* conv_b    = (const float*)d_in[3];
  const float* x_proj_w  = (const float*)d_in[4];
  const float* dt_proj_w = (const float*)d_in[5];
  const float* dt_proj_b = (const float*)d_in[6];
  const float* A_log     = (const float*)d_in[7];
  const float* D_param   = (const float*)d_in[8];
  const float* out_proj_w= (const float*)d_in[9];
  const float* norm_w    = (const float*)d_in[10];
  const float* norm_f_w  = (const float*)d_in[11];
  const float* inp_w     = (const float*)d_in[12];
  const float* inp_b     = (const float*)d_in[13];
  const float* cls_w     = (const float*)d_in[14];
  const float* cls_b     = (const float*)d_in[15];
  float* out = (float*)d_out;

  char* ws = (char*)d_ws;
  auto carve = [&](size_t nelem)->float* {
    float* p = (float*)ws;
    ws += ((nelem*sizeof(float) + 255)/256)*256;
    return p;
  };
  float* xt     = carve((size_t)ROWS*256);
  float* resid  = carve((size_t)ROWS*768);
  float* normed = carve((size_t)ROWS*768);
  float* hidden = carve((size_t)ROWS*768);
  float* xz     = carve((size_t)ROWS*3072);
  float* ucv    = carve((size_t)ROWS*1536);
  float* xp     = carve((size_t)ROWS*XP_N);
  float* delta  = carve((size_t)ROWS*1536);
  float* pooled = carve((size_t)B_SZ*768);
  float* yb = delta;  // safe alias: each delta element is read (same wave, same iter) before y's write

  transpose_x<<<dim3(16,8,4), dim3(32,32), 0, stream>>>(x, xt);
  // h = xt @ inp_w^T + inp_b  -> resid
  sgemm_tn<<<dim3(12,32), 256, 0, stream>>>(xt, 256, inp_w, inp_b, resid, ROWS, 768, 256, 0);

  for (int l = 0; l < 4; l++){
    add_rmsnorm<<<ROWS, 256, 0, stream>>>(resid, l ? hidden : nullptr, norm_w + (size_t)l*768, normed);
    // xz = normed @ ipw^T
    sgemm_tn<<<dim3(48,32), 256, 0, stream>>>(normed, 768, in_proj_w + (size_t)l*3072*768, nullptr,
                                              xz, ROWS, 3072, 768, 0);
    conv_silu<<<(ROWS*D_INNER)/256, 256, 0, stream>>>(xz, conv_w + (size_t)l*1536*4, conv_b + (size_t)l*1536, ucv);
    // xp = u @ xpw^T
    sgemm_tn<<<dim3(2,32), 256, 0, stream>>>(ucv, 1536, x_proj_w + (size_t)l*XP_N*1536, nullptr,
                                             xp, ROWS, XP_N, 1536, 0);
    // delta = softplus(dt @ dpw^T + dpb)
    sgemm_tn<<<dim3(24,32), 256, 0, stream>>>(xp, XP_N, dt_proj_w + (size_t)l*1536*48, dt_proj_b + (size_t)l*1536,
                                              delta, ROWS, 1536, 48, 1);
    mamba_scan<<<dim3(96,4), 256, 0, stream>>>(delta, ucv, xp, xz,
                                               A_log + (size_t)l*1536*16, D_param + (size_t)l*1536, yb);
    // hidden = y @ opw^T
    sgemm_tn<<<dim3(12,32), 256, 0, stream>>>(yb, 1536, out_proj_w + (size_t)l*768*1536, nullptr,
                                              hidden, ROWS, 768, 1536, 0);
  }

  add_rmsnorm<<<ROWS, 256, 0, stream>>>(resid, hidden, norm_f_w, normed);
  pool_mean<<<12, 256, 0, stream>>>(normed, pooled);
  cls_head<<<40, 64, 0, stream>>>(pooled, cls_w, cls_b, out);
}

// Round 2
// 2266.008 us; speedup vs baseline: 1.4433x; 1.4433x over previous
//
#include <hip/hip_runtime.h>
#include <math.h>

#define D_MODEL 768
#define D_INNER 1536
#define B_SZ 4
#define T_SZ 512
#define ROWS (B_SZ*T_SZ)   // 2048
#define XP_N 80
#define CH 8               // scan chunks
#define CT 64              // T per chunk

__device__ __forceinline__ float sigmoidf_(float x){ return 1.0f/(1.0f+__expf(-x)); }
__device__ __forceinline__ float siluf_(float x){ return x*sigmoidf_(x); }

// ---------------- transpose: x (B,256,512) -> xt (B,512,256) ----------------
__global__ void transpose_x(const float* __restrict__ x, float* __restrict__ xt){
  __shared__ float s[32][33];
  int b = blockIdx.z;
  int t0 = blockIdx.x*32, c0 = blockIdx.y*32;
  int tx = threadIdx.x, ty = threadIdx.y;
  s[ty][tx] = x[((size_t)b*256 + (c0+ty))*512 + (t0+tx)];
  __syncthreads();
  xt[((size_t)b*512 + (t0+ty))*256 + (c0+tx)] = s[tx][ty];
}

// ---------------- SGEMM: C[M,N] = A[M,K] (row-major, stride lda) * W[N,K]^T + bias ----------------
// act: 0 = none, 1 = softplus
__global__ __launch_bounds__(256) void sgemm_tn(
    const float* __restrict__ A, int lda,
    const float* __restrict__ W,
    const float* __restrict__ bias,
    float* __restrict__ C, int M, int N, int K, int act)
{
  __shared__ float As[16][64];
  __shared__ float Ws[16][64];
  const int bm = blockIdx.y*64, bn = blockIdx.x*64;
  const int tid = threadIdx.x;
  const int tx = tid & 15, ty = tid >> 4;
  const int lm = tid & 63, lk = (tid >> 6) << 2;
  float acc[4][4] = {};
  const float* Ap = A + (size_t)(bm+lm)*lda + lk;
  const float* Wp = W + (size_t)(bn+lm)*K + lk;
  const bool wok = (bn+lm) < N;
  for (int k0 = 0; k0 < K; k0 += 16){
    float4 av = *(const float4*)(Ap + k0);
    float4 wv = wok ? *(const float4*)(Wp + k0) : make_float4(0.f,0.f,0.f,0.f);
    As[lk+0][lm]=av.x; As[lk+1][lm]=av.y; As[lk+2][lm]=av.z; As[lk+3][lm]=av.w;
    Ws[lk+0][lm]=wv.x; Ws[lk+1][lm]=wv.y; Ws[lk+2][lm]=wv.z; Ws[lk+3][lm]=wv.w;
    __syncthreads();
    #pragma unroll
    for (int k = 0; k < 16; k++){
      float a[4], w[4];
      #pragma unroll
      for (int i=0;i<4;i++) a[i] = As[k][ty*4+i];
      #pragma unroll
      for (int j=0;j<4;j++) w[j] = Ws[k][tx*4+j];
      #pragma unroll
      for (int i=0;i<4;i++)
        #pragma unroll
        for (int j=0;j<4;j++)
          acc[i][j] += a[i]*w[j];
    }
    __syncthreads();
  }
  #pragma unroll
  for (int i=0;i<4;i++){
    const int r = bm + ty*4 + i;
    #pragma unroll
    for (int j=0;j<4;j++){
      const int n = bn + tx*4 + j;
      if (n < N){
        float v = acc[i][j] + (bias ? bias[n] : 0.f);
        if (act == 1){ v = (v > 20.f) ? v : log1pf(__expf(v)); }
        C[(size_t)r*N + n] = v;
      }
    }
  }
}

// ---------------- residual add + RMSNorm ----------------
__global__ __launch_bounds__(256) void add_rmsnorm(
    float* __restrict__ resid, const float* __restrict__ add,
    const float* __restrict__ w, float* __restrict__ out)
{
  const int row = blockIdx.x;
  const int tid = threadIdx.x;
  float v[3];
  float ss = 0.f;
  #pragma unroll
  for (int i=0;i<3;i++){
    const int c = tid + i*256;
    float r = resid[(size_t)row*768 + c];
    if (add) r += add[(size_t)row*768 + c];
    v[i] = r;
    ss += r*r;
  }
  #pragma unroll
  for (int off=32; off>=1; off>>=1) ss += __shfl_xor(ss, off);
  __shared__ float sred[4];
  const int lane = tid & 63, wv = tid >> 6;
  if (lane == 0) sred[wv] = ss;
  __syncthreads();
  const float tot = sred[0]+sred[1]+sred[2]+sred[3];
  const float scale = rsqrtf(tot*(1.0f/768.0f) + 1e-5f);
  #pragma unroll
  for (int i=0;i<3;i++){
    const int c = tid + i*256;
    if (add) resid[(size_t)row*768 + c] = v[i];
    out[(size_t)row*768 + c] = v[i]*scale*w[c];
  }
}

// ---------------- causal depthwise conv (K=4) + silu ----------------
__global__ __launch_bounds__(256) void conv_silu(
    const float* __restrict__ xz, const float* __restrict__ cw,
    const float* __restrict__ cb, float* __restrict__ uo)
{
  const int idx = blockIdx.x*256 + threadIdx.x;
  if (idx >= ROWS*D_INNER) return;
  const int d = idx % D_INNER;
  const int row = idx / D_INNER;
  const int t = row & (T_SZ-1);
  float acc = cb[d];
  #pragma unroll
  for (int k=0;k<4;k++){
    const int tt = t - 3 + k;
    if (tt >= 0)
      acc += xz[(size_t)(row - 3 + k)*3072 + d] * cw[d*4 + k];
  }
  uo[idx] = siluf_(acc);
}

// ---------------- chunked selective scan ----------------
// Pass 1: per-chunk local scan from h=0; emit P = prod(dA) and h_end.
// grid (96, B, CH-1): last chunk's P/h_end never consumed.
__global__ __launch_bounds__(256) void scan_pass1(
    const float* __restrict__ delta, const float* __restrict__ u,
    const float* __restrict__ xp, const float* __restrict__ alog,
    float* __restrict__ Pend, float* __restrict__ Hend)
{
  const int tid = threadIdx.x;
  const int n = tid & 15;
  const int d = blockIdx.x*16 + (tid >> 4);
  const int b = blockIdx.y;
  const int c = blockIdx.z;
  const float Av = -__expf(alog[d*16 + n]);
  float h = 0.f, P = 1.f;
  const size_t row0 = (size_t)b*T_SZ + (size_t)c*CT;
  const float* dp = delta + row0*D_INNER + d;
  const float* up = u     + row0*D_INNER + d;
  const float* bp = xp    + row0*XP_N + 48 + n;
  for (int t=0; t<CT; t++){
    const float dv = dp[(size_t)t*D_INNER];
    const float uv = up[(size_t)t*D_INNER];
    const float Bv = bp[(size_t)t*XP_N];
    const float dA = __expf(dv*Av);
    P *= dA;
    h = dA*h + (dv*uv)*Bv;
  }
  const size_t idx = ((size_t)(b*CH + c)*D_INNER + d)*16 + n;
  Pend[idx] = P;
  Hend[idx] = h;
}

// Pass 2: sequential combine over chunks (parallel over 98304 (b,d,n) states).
__global__ __launch_bounds__(256) void scan_combine(
    const float* __restrict__ Pend, const float* __restrict__ Hend,
    float* __restrict__ Hin)
{
  const int gid = blockIdx.x*256 + threadIdx.x;       // 0..98303
  const int b = gid / (D_INNER*16);
  const int r = gid % (D_INNER*16);
  const size_t base = (size_t)b*CH*D_INNER*16 + r;
  const size_t step = (size_t)D_INNER*16;
  float h = 0.f;
  Hin[base] = 0.f;
  for (int c=0; c<CH-1; c++){
    h = Pend[base + (size_t)c*step]*h + Hend[base + (size_t)c*step];
    Hin[base + (size_t)(c+1)*step] = h;
  }
}

// Pass 3: re-run each chunk with correct initial state, emit y.
// yb may alias delta: per-t the wave reads delta before lane n==0 stores y.
__global__ __launch_bounds__(256) void scan_pass3(
    const float* delta, const float* __restrict__ u,
    const float* __restrict__ xp, const float* __restrict__ xz,
    const float* __restrict__ alog, const float* __restrict__ Dp,
    const float* __restrict__ Hin, float* yb)
{
  const int tid = threadIdx.x;
  const int n = tid & 15;
  const int d = blockIdx.x*16 + (tid >> 4);
  const int b = blockIdx.y;
  const int c = blockIdx.z;
  const float Av = -__expf(alog[d*16 + n]);
  const float Dv = Dp[d];
  float h = Hin[((size_t)(b*CH + c)*D_INNER + d)*16 + n];
  const size_t row0 = (size_t)b*T_SZ + (size_t)c*CT;
  const float* dp = delta + row0*D_INNER + d;
  const float* up = u     + row0*D_INNER + d;
  const float* bp = xp    + row0*XP_N + 48 + n;
  const float* cp = xp    + row0*XP_N + 64 + n;
  const float* zp = xz    + row0*3072 + 1536 + d;
  float* yp = yb + row0*D_INNER + d;
  for (int t=0; t<CT; t++){
    const float dv = dp[(size_t)t*D_INNER];
    const float uv = up[(size_t)t*D_INNER];
    const float Bv = bp[(size_t)t*XP_N];
    const float Cv = cp[(size_t)t*XP_N];
    const float dA = __expf(dv*Av);
    h = dA*h + (dv*uv)*Bv;
    float p = h*Cv;
    p += __shfl_xor(p, 1);
    p += __shfl_xor(p, 2);
    p += __shfl_xor(p, 4);
    p += __shfl_xor(p, 8);
    if (n == 0){
      const float zv = zp[(size_t)t*3072];
      yp[(size_t)t*D_INNER] = (p + uv*Dv) * siluf_(zv);
    }
  }
}

// ---------------- mean pool over T ----------------
__global__ void pool_mean(const float* __restrict__ normed, float* __restrict__ pooled){
  const int idx = blockIdx.x*256 + threadIdx.x;
  if (idx >= B_SZ*768) return;
  const int b = idx / 768, m = idx % 768;
  float s = 0.f;
  for (int t=0; t<T_SZ; t++) s += normed[((size_t)b*T_SZ + t)*768 + m];
  pooled[idx] = s * (1.0f/T_SZ);
}

// ---------------- classifier head: out (4,10) ----------------
__global__ void cls_head(const float* __restrict__ pooled, const float* __restrict__ cw,
                         const float* __restrict__ cb, float* __restrict__ out){
  const int o = blockIdx.x % 10, b = blockIdx.x / 10;
  const int lane = threadIdx.x; // 64
  float s = 0.f;
  for (int k = lane; k < 768; k += 64) s += pooled[b*768 + k]*cw[o*768 + k];
  #pragma unroll
  for (int off=32; off>=1; off>>=1) s += __shfl_xor(s, off);
  if (lane == 0) out[b*10 + o] = s + cb[o];
}

extern "C" void kernel_launch(void* const* d_in, const int* in_sizes, int n_in,
                              void* d_out, int out_size, void* d_ws, size_t ws_size,
                              hipStream_t stream) {
  const float* x         = (const float*)d_in[0];
  const float* in_proj_w = (const float*)d_in[1];
  const float* conv_w    = (const float*)d_in[2];
  const float* conv_b    = (const float*)d_in[3];
  const float* x_proj_w  = (const float*)d_in[4];
  const float* dt_proj_w = (const float*)d_in[5];
  const float* dt_proj_b = (const float*)d_in[6];
  const float* A_log     = (const float*)d_in[7];
  const float* D_param   = (const float*)d_in[8];
  const float* out_proj_w= (const float*)d_in[9];
  const float* norm_w    = (const float*)d_in[10];
  const float* norm_f_w  = (const float*)d_in[11];
  const float* inp_w     = (const float*)d_in[12];
  const float* inp_b     = (const float*)d_in[13];
  const float* cls_w     = (const float*)d_in[14];
  const float* cls_b     = (const float*)d_in[15];
  float* out = (float*)d_out;

  char* ws = (char*)d_ws;
  auto carve = [&](size_t nelem)->float* {
    float* p = (float*)ws;
    ws += ((nelem*sizeof(float) + 255)/256)*256;
    return p;
  };
  float* xt     = carve((size_t)ROWS*256);
  float* resid  = carve((size_t)ROWS*768);
  float* normed = carve((size_t)ROWS*768);
  float* hidden = carve((size_t)ROWS*768);
  float* xz     = carve((size_t)ROWS*3072);
  float* ucv    = carve((size_t)ROWS*1536);
  float* xp     = carve((size_t)ROWS*XP_N);
  float* delta  = carve((size_t)ROWS*1536);
  float* pooled = carve((size_t)B_SZ*768);
  float* yb = delta;  // safe alias (see scan_pass3)

  // Scan scratch aliased onto buffers dead during the scan:
  //   normed: dead after in_proj GEMM until next layer's add_rmsnorm (1.57M floats)
  //   hidden: dead after layer-start add_rmsnorm until out_proj writes it (1.57M floats)
  // Needed: Pend/Hend/Hin each B*CH*D_INNER*16 = 786432 floats.
  float* Pend = normed;                 // normed[0 : 786432]
  float* Hin  = normed + 786432;        // normed[786432 : 1572864]
  float* Hend = hidden;                 // hidden[0 : 786432]

  transpose_x<<<dim3(16,8,4), dim3(32,32), 0, stream>>>(x, xt);
  sgemm_tn<<<dim3(12,32), 256, 0, stream>>>(xt, 256, inp_w, inp_b, resid, ROWS, 768, 256, 0);

  for (int l = 0; l < 4; l++){
    add_rmsnorm<<<ROWS, 256, 0, stream>>>(resid, l ? hidden : nullptr, norm_w + (size_t)l*768, normed);
    sgemm_tn<<<dim3(48,32), 256, 0, stream>>>(normed, 768, in_proj_w + (size_t)l*3072*768, nullptr,
                                              xz, ROWS, 3072, 768, 0);
    conv_silu<<<(ROWS*D_INNER)/256, 256, 0, stream>>>(xz, conv_w + (size_t)l*1536*4, conv_b + (size_t)l*1536, ucv);
    sgemm_tn<<<dim3(2,32), 256, 0, stream>>>(ucv, 1536, x_proj_w + (size_t)l*XP_N*1536, nullptr,
                                             xp, ROWS, XP_N, 1536, 0);
    sgemm_tn<<<dim3(24,32), 256, 0, stream>>>(xp, XP_N, dt_proj_w + (size_t)l*1536*48, dt_proj_b + (size_t)l*1536,
                                              delta, ROWS, 1536, 48, 1);
    scan_pass1<<<dim3(96,B_SZ,CH-1), 256, 0, stream>>>(delta, ucv, xp,
                                               A_log + (size_t)l*1536*16, Pend, Hend);
    scan_combine<<<(B_SZ*D_INNER*16)/256, 256, 0, stream>>>(Pend, Hend, Hin);
    scan_pass3<<<dim3(96,B_SZ,CH), 256, 0, stream>>>(delta, ucv, xp, xz,
                                               A_log + (size_t)l*1536*16, D_param + (size_t)l*1536, Hin, yb);
    sgemm_tn<<<dim3(12,32), 256, 0, stream>>>(yb, 1536, out_proj_w + (size_t)l*768*1536, nullptr,
                                              hidden, ROWS, 768, 1536, 0);
  }

  add_rmsnorm<<<ROWS, 256, 0, stream>>>(resid, hidden, norm_f_w, normed);
  pool_mean<<<12, 256, 0, stream>>>(normed, pooled);
  cls_head<<<40, 64, 0, stream>>>(pooled, cls_w, cls_b, out);
}

// Round 3
// 1581.757 us; speedup vs baseline: 2.0676x; 1.4326x over previous
//
#include <hip/hip_runtime.h>
#include <math.h>

#define D_MODEL 768
#define D_INNER 1536
#define B_SZ 4
#define T_SZ 512
#define ROWS (B_SZ*T_SZ)   // 2048
#define XP_N 80
#define CH 8               // scan chunks
#define CT 64              // T per chunk

typedef __attribute__((ext_vector_type(8))) short bf16x8;
typedef __attribute__((ext_vector_type(4))) float f32x4;

__device__ __forceinline__ float sigmoidf_(float x){ return 1.0f/(1.0f+__expf(-x)); }
__device__ __forceinline__ float siluf_(float x){ return x*sigmoidf_(x); }
__device__ __forceinline__ unsigned short f2bf(float f){
  unsigned u = __builtin_bit_cast(unsigned, f);
  u = (u + 0x7FFFu + ((u >> 16) & 1u)) >> 16;   // RNE
  return (unsigned short)u;
}

// ---------------- transpose: x (B,256,512) -> xt (B,512,256) ----------------
__global__ void transpose_x(const float* __restrict__ x, float* __restrict__ xt){
  __shared__ float s[32][33];
  int b = blockIdx.z;
  int t0 = blockIdx.x*32, c0 = blockIdx.y*32;
  int tx = threadIdx.x, ty = threadIdx.y;
  s[ty][tx] = x[((size_t)b*256 + (c0+ty))*512 + (t0+tx)];
  __syncthreads();
  xt[((size_t)b*512 + (t0+ty))*256 + (c0+tx)] = s[tx][ty];
}

// ---------------- fp32 -> bf16 cast (n divisible by 1024) ----------------
__global__ __launch_bounds__(256) void cast_bf16(const float* __restrict__ in,
                                                 unsigned short* __restrict__ o, int n){
  const int i4 = (blockIdx.x*256 + threadIdx.x)*4;
  if (i4 >= n) return;
  float4 v = *(const float4*)(in + i4);
  ushort4 r;
  r.x = f2bf(v.x); r.y = f2bf(v.y); r.z = f2bf(v.z); r.w = f2bf(v.w);
  *(ushort4*)(o + i4) = r;
}

// ---------------- bf16 MFMA GEMM: C[M,N] = A[M,K] * W[N,K]^T ----------------
// Requires M%128==0, N%128==0, K%32==0. 256 threads = 4 waves (2x2 of 64x64).
#define LDP 40   // padded LDS row (elems): 80B rows -> 16B-aligned, 2-way banks max
__global__ __launch_bounds__(256) void gemm_bf16(
    const unsigned short* __restrict__ A, const unsigned short* __restrict__ Wb,
    float* __restrict__ C, int M, int N, int K)
{
  __shared__ unsigned short As[128*LDP];
  __shared__ unsigned short Ws[128*LDP];
  const int tid = threadIdx.x;
  const int bm = blockIdx.y*128, bn = blockIdx.x*128;
  const int wave = tid >> 6, lane = tid & 63;
  const int wm = (wave >> 1)*64, wn = (wave & 1)*64;
  const int fr = lane & 15, quad = lane >> 4;
  f32x4 acc[4][4] = {};
  const int srow = tid >> 1, scol = (tid & 1)*16;
  const unsigned short* Ag = A  + (size_t)(bm + srow)*K + scol;
  const unsigned short* Wg = Wb + (size_t)(bn + srow)*K + scol;
  unsigned short* Asw = As + srow*LDP + scol;
  unsigned short* Wsw = Ws + srow*LDP + scol;

  for (int k0 = 0; k0 < K; k0 += 32){
    float4 av0 = *(const float4*)(Ag + k0);
    float4 av1 = *(const float4*)(Ag + k0 + 8);
    float4 wv0 = *(const float4*)(Wg + k0);
    float4 wv1 = *(const float4*)(Wg + k0 + 8);
    __syncthreads();                       // prior iter's frag reads done
    *(float4*)(Asw)     = av0; *(float4*)(Asw + 8) = av1;
    *(float4*)(Wsw)     = wv0; *(float4*)(Wsw + 8) = wv1;
    __syncthreads();                       // staging visible
    bf16x8 a[4], b[4];
    #pragma unroll
    for (int i=0;i<4;i++)
      a[i] = *(const bf16x8*)(As + (wm + i*16 + fr)*LDP + quad*8);
    #pragma unroll
    for (int j=0;j<4;j++)
      b[j] = *(const bf16x8*)(Ws + (wn + j*16 + fr)*LDP + quad*8);
    #pragma unroll
    for (int i=0;i<4;i++)
      #pragma unroll
      for (int j=0;j<4;j++)
        acc[i][j] = __builtin_amdgcn_mfma_f32_16x16x32_bf16(a[i], b[j], acc[i][j], 0, 0, 0);
  }
  // C/D layout: col = lane&15, row = quad*4 + reg  [m89-verified]
  #pragma unroll
  for (int i=0;i<4;i++){
    #pragma unroll
    for (int r=0;r<4;r++){
      const int row = bm + wm + i*16 + quad*4 + r;
      float* Cp = C + (size_t)row*N + bn + wn + fr;
      #pragma unroll
      for (int j=0;j<4;j++)
        Cp[j*16] = acc[i][j][r];
    }
  }
}

// ---------------- fp32 SGEMM (x_proj / dt_proj / input) ----------------
__global__ __launch_bounds__(256) void sgemm_tn(
    const float* __restrict__ A, int lda,
    const float* __restrict__ W,
    const float* __restrict__ bias,
    float* __restrict__ C, int M, int N, int K, int act)
{
  __shared__ float As[16][64];
  __shared__ float Wsh[16][64];
  const int bm = blockIdx.y*64, bn = blockIdx.x*64;
  const int tid = threadIdx.x;
  const int tx = tid & 15, ty = tid >> 4;
  const int lm = tid & 63, lk = (tid >> 6) << 2;
  float acc[4][4] = {};
  const float* Ap = A + (size_t)(bm+lm)*lda + lk;
  const float* Wp = W + (size_t)(bn+lm)*K + lk;
  const bool wok = (bn+lm) < N;
  for (int k0 = 0; k0 < K; k0 += 16){
    float4 av = *(const float4*)(Ap + k0);
    float4 wv = wok ? *(const float4*)(Wp + k0) : make_float4(0.f,0.f,0.f,0.f);
    As[lk+0][lm]=av.x; As[lk+1][lm]=av.y; As[lk+2][lm]=av.z; As[lk+3][lm]=av.w;
    Wsh[lk+0][lm]=wv.x; Wsh[lk+1][lm]=wv.y; Wsh[lk+2][lm]=wv.z; Wsh[lk+3][lm]=wv.w;
    __syncthreads();
    #pragma unroll
    for (int k = 0; k < 16; k++){
      float a[4], w[4];
      #pragma unroll
      for (int i=0;i<4;i++) a[i] = As[k][ty*4+i];
      #pragma unroll
      for (int j=0;j<4;j++) w[j] = Wsh[k][tx*4+j];
      #pragma unroll
      for (int i=0;i<4;i++)
        #pragma unroll
        for (int j=0;j<4;j++)
          acc[i][j] += a[i]*w[j];
    }
    __syncthreads();
  }
  #pragma unroll
  for (int i=0;i<4;i++){
    const int r = bm + ty*4 + i;
    #pragma unroll
    for (int j=0;j<4;j++){
      const int n = bn + tx*4 + j;
      if (n < N){
        float v = acc[i][j] + (bias ? bias[n] : 0.f);
        if (act == 1){ v = (v > 20.f) ? v : log1pf(__expf(v)); }
        C[(size_t)r*N + n] = v;
      }
    }
  }
}

// ---------------- residual add + RMSNorm (bf16 or fp32 out) ----------------
__global__ __launch_bounds__(256) void add_rmsnorm(
    float* __restrict__ resid, const float* __restrict__ add,
    const float* __restrict__ w, float* __restrict__ out,
    unsigned short* __restrict__ obf)
{
  const int row = blockIdx.x;
  const int tid = threadIdx.x;
  float v[3];
  float ss = 0.f;
  #pragma unroll
  for (int i=0;i<3;i++){
    const int c = tid + i*256;
    float r = resid[(size_t)row*768 + c];
    if (add) r += add[(size_t)row*768 + c];
    v[i] = r;
    ss += r*r;
  }
  #pragma unroll
  for (int off=32; off>=1; off>>=1) ss += __shfl_xor(ss, off);
  __shared__ float sred[4];
  const int lane = tid & 63, wv = tid >> 6;
  if (lane == 0) sred[wv] = ss;
  __syncthreads();
  const float tot = sred[0]+sred[1]+sred[2]+sred[3];
  const float scale = rsqrtf(tot*(1.0f/768.0f) + 1e-5f);
  #pragma unroll
  for (int i=0;i<3;i++){
    const int c = tid + i*256;
    if (add) resid[(size_t)row*768 + c] = v[i];
    const float o = v[i]*scale*w[c];
    if (obf) obf[(size_t)row*768 + c] = f2bf(o);
    else     out[(size_t)row*768 + c] = o;
  }
}

// ---------------- causal depthwise conv (K=4) + silu ----------------
__global__ __launch_bounds__(256) void conv_silu(
    const float* __restrict__ xz, const float* __restrict__ cw,
    const float* __restrict__ cb, float* __restrict__ uo)
{
  const int idx = blockIdx.x*256 + threadIdx.x;
  if (idx >= ROWS*D_INNER) return;
  const int d = idx % D_INNER;
  const int row = idx / D_INNER;
  const int t = row & (T_SZ-1);
  float acc = cb[d];
  #pragma unroll
  for (int k=0;k<4;k++){
    const int tt = t - 3 + k;
    if (tt >= 0)
      acc += xz[(size_t)(row - 3 + k)*3072 + d] * cw[d*4 + k];
  }
  uo[idx] = siluf_(acc);
}

// ---------------- chunked selective scan ----------------
__global__ __launch_bounds__(256) void scan_pass1(
    const float* __restrict__ delta, const float* __restrict__ u,
    const float* __restrict__ xp, const float* __restrict__ alog,
    float* __restrict__ Pend, float* __restrict__ Hend)
{
  const int tid = threadIdx.x;
  const int n = tid & 15;
  const int d = blockIdx.x*16 + (tid >> 4);
  const int b = blockIdx.y;
  const int c = blockIdx.z;
  const float Av = -__expf(alog[d*16 + n]);
  float h = 0.f, P = 1.f;
  const size_t row0 = (size_t)b*T_SZ + (size_t)c*CT;
  const float* dp = delta + row0*D_INNER + d;
  const float* up = u     + row0*D_INNER + d;
  const float* bp = xp    + row0*XP_N + 48 + n;
  for (int t=0; t<CT; t++){
    const float dv = dp[(size_t)t*D_INNER];
    const float uv = up[(size_t)t*D_INNER];
    const float Bv = bp[(size_t)t*XP_N];
    const float dA = __expf(dv*Av);
    P *= dA;
    h = dA*h + (dv*uv)*Bv;
  }
  const size_t idx = ((size_t)(b*CH + c)*D_INNER + d)*16 + n;
  Pend[idx] = P;
  Hend[idx] = h;
}

__global__ __launch_bounds__(256) void scan_combine(
    const float* __restrict__ Pend, const float* __restrict__ Hend,
    float* __restrict__ Hin)
{
  const int gid = blockIdx.x*256 + threadIdx.x;       // 0..98303
  const int b = gid / (D_INNER*16);
  const int r = gid % (D_INNER*16);
  const size_t base = (size_t)b*CH*D_INNER*16 + r;
  const size_t step = (size_t)D_INNER*16;
  float h = 0.f;
  Hin[base] = 0.f;
  for (int c=0; c<CH-1; c++){
    h = Pend[base + (size_t)c*step]*h + Hend[base + (size_t)c*step];
    Hin[base + (size_t)(c+1)*step] = h;
  }
}

// Pass 3: emit y in bf16 (feeds out_proj MFMA GEMM).
__global__ __launch_bounds__(256) void scan_pass3(
    const float* __restrict__ delta, const float* __restrict__ u,
    const float* __restrict__ xp, const float* __restrict__ xz,
    const float* __restrict__ alog, const float* __restrict__ Dp,
    const float* __restrict__ Hin, unsigned short* __restrict__ yb)
{
  const int tid = threadIdx.x;
  const int n = tid & 15;
  const int d = blockIdx.x*16 + (tid >> 4);
  const int b = blockIdx.y;
  const int c = blockIdx.z;
  const float Av = -__expf(alog[d*16 + n]);
  const float Dv = Dp[d];
  float h = Hin[((size_t)(b*CH + c)*D_INNER + d)*16 + n];
  const size_t row0 = (size_t)b*T_SZ + (size_t)c*CT;
  const float* dp = delta + row0*D_INNER + d;
  const float* up = u     + row0*D_INNER + d;
  const float* bp = xp    + row0*XP_N + 48 + n;
  const float* cp = xp    + row0*XP_N + 64 + n;
  const float* zp = xz    + row0*3072 + 1536 + d;
  unsigned short* yp = yb + row0*D_INNER + d;
  for (int t=0; t<CT; t++){
    const float dv = dp[(size_t)t*D_INNER];
    const float uv = up[(size_t)t*D_INNER];
    const float Bv = bp[(size_t)t*XP_N];
    const float Cv = cp[(size_t)t*XP_N];
    const float dA = __expf(dv*Av);
    h = dA*h + (dv*uv)*Bv;
    float p = h*Cv;
    p += __shfl_xor(p, 1);
    p += __shfl_xor(p, 2);
    p += __shfl_xor(p, 4);
    p += __shfl_xor(p, 8);
    if (n == 0){
      const float zv = zp[(size_t)t*3072];
      yp[(size_t)t*D_INNER] = f2bf((p + uv*Dv) * siluf_(zv));
    }
  }
}

// ---------------- mean pool over T ----------------
__global__ void pool_mean(const float* __restrict__ normed, float* __restrict__ pooled){
  const int idx = blockIdx.x*256 + threadIdx.x;
  if (idx >= B_SZ*768) return;
  const int b = idx / 768, m = idx % 768;
  float s = 0.f;
  for (int t=0; t<T_SZ; t++) s += normed[((size_t)b*T_SZ + t)*768 + m];
  pooled[idx] = s * (1.0f/T_SZ);
}

// ---------------- classifier head: out (4,10) ----------------
__global__ void cls_head(const float* __restrict__ pooled, const float* __restrict__ cw,
                         const float* __restrict__ cb, float* __restrict__ out){
  const int o = blockIdx.x % 10, b = blockIdx.x / 10;
  const int lane = threadIdx.x; // 64
  float s = 0.f;
  for (int k = lane; k < 768; k += 64) s += pooled[b*768 + k]*cw[o*768 + k];
  #pragma unroll
  for (int off=32; off>=1; off>>=1) s += __shfl_xor(s, off);
  if (lane == 0) out[b*10 + o] = s + cb[o];
}

extern "C" void kernel_launch(void* const* d_in, const int* in_sizes, int n_in,
                              void* d_out, int out_size, void* d_ws, size_t ws_size,
                              hipStream_t stream) {
  const float* x         = (const float*)d_in[0];
  const float* in_proj_w = (const float*)d_in[1];
  const float* conv_w    = (const float*)d_in[2];
  const float* conv_b    = (const float*)d_in[3];
  const float* x_proj_w  = (const float*)d_in[4];
  const float* dt_proj_w = (const float*)d_in[5];
  const float* dt_proj_b = (const float*)d_in[6];
  const float* A_log     = (const float*)d_in[7];
  const float* D_param   = (const float*)d_in[8];
  const float* out_proj_w= (const float*)d_in[9];
  const float* norm_w    = (const float*)d_in[10];
  const float* norm_f_w  = (const float*)d_in[11];
  const float* inp_w     = (const float*)d_in[12];
  const float* inp_b     = (const float*)d_in[13];
  const float* cls_w     = (const float*)d_in[14];
  const float* cls_b     = (const float*)d_in[15];
  float* out = (float*)d_out;

  char* ws = (char*)d_ws;
  auto carve = [&](size_t nelem)->float* {
    float* p = (float*)ws;
    ws += ((nelem*sizeof(float) + 255)/256)*256;
    return p;
  };
  float* xt     = carve((size_t)ROWS*256);
  float* resid  = carve((size_t)ROWS*768);
  float* normed = carve((size_t)ROWS*768);   // bf16 normed in lower half; Hin in upper; fp32 at final
  float* hidden = carve((size_t)ROWS*768);
  float* xz     = carve((size_t)ROWS*3072);
  float* ucv    = carve((size_t)ROWS*1536);
  float* xp     = carve((size_t)ROWS*XP_N);
  float* delta  = carve((size_t)ROWS*1536);
  float* ybf_f  = carve((size_t)ROWS*1536/2);    // bf16 y (2048x1536)
  float* wbf_f  = carve((size_t)(3072*768)/2);   // reused per-layer bf16 weights
  float* pooled = carve((size_t)B_SZ*768);

  unsigned short* normedb = (unsigned short*)normed;   // 2048x768 bf16 (3.1 MB of 6.3)
  unsigned short* ybf = (unsigned short*)ybf_f;
  unsigned short* wbf = (unsigned short*)wbf_f;
  // scan scratch on dead regions:
  float* Pend = hidden;                 // hidden dead between layer-start rmsnorm and out_proj
  float* Hend = hidden + 786432;
  float* Hin  = normed + 786432;        // upper half of normed (bf16 normed uses lower half)

  transpose_x<<<dim3(16,8,4), dim3(32,32), 0, stream>>>(x, xt);
  sgemm_tn<<<dim3(12,32), 256, 0, stream>>>(xt, 256, inp_w, inp_b, resid, ROWS, 768, 256, 0);

  for (int l = 0; l < 4; l++){
    add_rmsnorm<<<ROWS, 256, 0, stream>>>(resid, l ? hidden : nullptr, norm_w + (size_t)l*768,
                                          nullptr, normedb);
    cast_bf16<<<(3072*768)/1024, 256, 0, stream>>>(in_proj_w + (size_t)l*3072*768, wbf, 3072*768);
    gemm_bf16<<<dim3(24,16), 256, 0, stream>>>(normedb, wbf, xz, ROWS, 3072, 768);
    conv_silu<<<(ROWS*D_INNER)/256, 256, 0, stream>>>(xz, conv_w + (size_t)l*1536*4, conv_b + (size_t)l*1536, ucv);
    sgemm_tn<<<dim3(2,32), 256, 0, stream>>>(ucv, 1536, x_proj_w + (size_t)l*XP_N*1536, nullptr,
                                             xp, ROWS, XP_N, 1536, 0);
    sgemm_tn<<<dim3(24,32), 256, 0, stream>>>(xp, XP_N, dt_proj_w + (size_t)l*1536*48, dt_proj_b + (size_t)l*1536,
                                              delta, ROWS, 1536, 48, 1);
    scan_pass1<<<dim3(96,B_SZ,CH-1), 256, 0, stream>>>(delta, ucv, xp,
                                               A_log + (size_t)l*1536*16, Pend, Hend);
    scan_combine<<<(B_SZ*D_INNER*16)/256, 256, 0, stream>>>(Pend, Hend, Hin);
    scan_pass3<<<dim3(96,B_SZ,CH), 256, 0, stream>>>(delta, ucv, xp, xz,
                                               A_log + (size_t)l*1536*16, D_param + (size_t)l*1536, Hin, ybf);
    cast_bf16<<<(768*1536)/1024, 256, 0, stream>>>(out_proj_w + (size_t)l*768*1536, wbf, 768*1536);
    gemm_bf16<<<dim3(6,16), 256, 0, stream>>>(ybf, wbf, hidden, ROWS, 768, 1536);
  }

  add_rmsnorm<<<ROWS, 256, 0, stream>>>(resid, hidden, norm_f_w, normed, nullptr);
  pool_mean<<<12, 256, 0, stream>>>(normed, pooled);
  cls_head<<<40, 64, 0, stream>>>(pooled, cls_w, cls_b, out);
}

// Round 4
// 975.464 us; speedup vs baseline: 3.3527x; 1.6215x over previous
//
#include <hip/hip_runtime.h>
#include <math.h>

#define D_MODEL 768
#define D_INNER 1536
#define B_SZ 4
#define T_SZ 512
#define ROWS (B_SZ*T_SZ)   // 2048
#define XP_N 80
#define CH 16              // scan chunks
#define CT 32              // T per chunk
#define XS 8               // x_proj split-K factor
#define XKC (D_INNER/XS)   // 192

typedef __attribute__((ext_vector_type(8))) short bf16x8;
typedef __attribute__((ext_vector_type(4))) float f32x4;

__device__ __forceinline__ float sigmoidf_(float x){ return 1.0f/(1.0f+__expf(-x)); }
__device__ __forceinline__ float siluf_(float x){ return x*sigmoidf_(x); }
__device__ __forceinline__ unsigned short f2bf(float f){
  unsigned u = __builtin_bit_cast(unsigned, f);
  u = (u + 0x7FFFu + ((u >> 16) & 1u)) >> 16;   // RNE
  return (unsigned short)u;
}

// ---------------- transpose: x (B,256,512) -> xt (B,512,256) ----------------
__global__ void transpose_x(const float* __restrict__ x, float* __restrict__ xt){
  __shared__ float s[32][33];
  int b = blockIdx.z;
  int t0 = blockIdx.x*32, c0 = blockIdx.y*32;
  int tx = threadIdx.x, ty = threadIdx.y;
  s[ty][tx] = x[((size_t)b*256 + (c0+ty))*512 + (t0+tx)];
  __syncthreads();
  xt[((size_t)b*512 + (t0+ty))*256 + (c0+tx)] = s[tx][ty];
}

// ---------------- fp32 -> bf16 cast (n divisible by 4) ----------------
__global__ __launch_bounds__(256) void cast_bf16(const float* __restrict__ in,
                                                 unsigned short* __restrict__ o, int n){
  const int i4 = (blockIdx.x*256 + threadIdx.x)*4;
  if (i4 >= n) return;
  float4 v = *(const float4*)(in + i4);
  ushort4 r;
  r.x = f2bf(v.x); r.y = f2bf(v.y); r.z = f2bf(v.z); r.w = f2bf(v.w);
  *(ushort4*)(o + i4) = r;
}

// ---------------- bf16 MFMA GEMM: C[M,N] = A[M,K] * W[N,K]^T ----------------
// Requires M%128==0, N%128==0, K%32==0. 256 threads = 4 waves (2x2 of 64x64).
#define LDP 40
__global__ __launch_bounds__(256) void gemm_bf16(
    const unsigned short* __restrict__ A, const unsigned short* __restrict__ Wb,
    float* __restrict__ C, int M, int N, int K)
{
  __shared__ unsigned short As[128*LDP];
  __shared__ unsigned short Ws[128*LDP];
  const int tid = threadIdx.x;
  const int bm = blockIdx.y*128, bn = blockIdx.x*128;
  const int wave = tid >> 6, lane = tid & 63;
  const int wm = (wave >> 1)*64, wn = (wave & 1)*64;
  const int fr = lane & 15, quad = lane >> 4;
  f32x4 acc[4][4] = {};
  const int srow = tid >> 1, scol = (tid & 1)*16;
  const unsigned short* Ag = A  + (size_t)(bm + srow)*K + scol;
  const unsigned short* Wg = Wb + (size_t)(bn + srow)*K + scol;
  unsigned short* Asw = As + srow*LDP + scol;
  unsigned short* Wsw = Ws + srow*LDP + scol;

  for (int k0 = 0; k0 < K; k0 += 32){
    float4 av0 = *(const float4*)(Ag + k0);
    float4 av1 = *(const float4*)(Ag + k0 + 8);
    float4 wv0 = *(const float4*)(Wg + k0);
    float4 wv1 = *(const float4*)(Wg + k0 + 8);
    __syncthreads();
    *(float4*)(Asw)     = av0; *(float4*)(Asw + 8) = av1;
    *(float4*)(Wsw)     = wv0; *(float4*)(Wsw + 8) = wv1;
    __syncthreads();
    bf16x8 a[4], b[4];
    #pragma unroll
    for (int i=0;i<4;i++)
      a[i] = *(const bf16x8*)(As + (wm + i*16 + fr)*LDP + quad*8);
    #pragma unroll
    for (int j=0;j<4;j++)
      b[j] = *(const bf16x8*)(Ws + (wn + j*16 + fr)*LDP + quad*8);
    #pragma unroll
    for (int i=0;i<4;i++)
      #pragma unroll
      for (int j=0;j<4;j++)
        acc[i][j] = __builtin_amdgcn_mfma_f32_16x16x32_bf16(a[i], b[j], acc[i][j], 0, 0, 0);
  }
  #pragma unroll
  for (int i=0;i<4;i++){
    #pragma unroll
    for (int r=0;r<4;r++){
      const int row = bm + wm + i*16 + quad*4 + r;
      float* Cp = C + (size_t)row*N + bn + wn + fr;
      #pragma unroll
      for (int j=0;j<4;j++)
        Cp[j*16] = acc[i][j][r];
    }
  }
}

// ---------------- fp32 SGEMM (dt_proj / input) ----------------
__global__ __launch_bounds__(256) void sgemm_tn(
    const float* __restrict__ A, int lda,
    const float* __restrict__ W,
    const float* __restrict__ bias,
    float* __restrict__ C, int M, int N, int K, int act)
{
  __shared__ float As[16][64];
  __shared__ float Wsh[16][64];
  const int bm = blockIdx.y*64, bn = blockIdx.x*64;
  const int tid = threadIdx.x;
  const int tx = tid & 15, ty = tid >> 4;
  const int lm = tid & 63, lk = (tid >> 6) << 2;
  float acc[4][4] = {};
  const float* Ap = A + (size_t)(bm+lm)*lda + lk;
  const float* Wp = W + (size_t)(bn+lm)*K + lk;
  const bool wok = (bn+lm) < N;
  for (int k0 = 0; k0 < K; k0 += 16){
    float4 av = *(const float4*)(Ap + k0);
    float4 wv = wok ? *(const float4*)(Wp + k0) : make_float4(0.f,0.f,0.f,0.f);
    As[lk+0][lm]=av.x; As[lk+1][lm]=av.y; As[lk+2][lm]=av.z; As[lk+3][lm]=av.w;
    Wsh[lk+0][lm]=wv.x; Wsh[lk+1][lm]=wv.y; Wsh[lk+2][lm]=wv.z; Wsh[lk+3][lm]=wv.w;
    __syncthreads();
    #pragma unroll
    for (int k = 0; k < 16; k++){
      float a[4], w[4];
      #pragma unroll
      for (int i=0;i<4;i++) a[i] = As[k][ty*4+i];
      #pragma unroll
      for (int j=0;j<4;j++) w[j] = Wsh[k][tx*4+j];
      #pragma unroll
      for (int i=0;i<4;i++)
        #pragma unroll
        for (int j=0;j<4;j++)
          acc[i][j] += a[i]*w[j];
    }
    __syncthreads();
  }
  #pragma unroll
  for (int i=0;i<4;i++){
    const int r = bm + ty*4 + i;
    #pragma unroll
    for (int j=0;j<4;j++){
      const int n = bn + tx*4 + j;
      if (n < N){
        float v = acc[i][j] + (bias ? bias[n] : 0.f);
        if (act == 1){ v = (v > 20.f) ? v : log1pf(__expf(v)); }
        C[(size_t)r*N + n] = v;
      }
    }
  }
}

// ---------------- x_proj split-K fp32: part[s] = A[:,s*192:(s+1)*192] @ W_chunk^T ----------------
// grid (2, 32, XS); A = ucv (2048x1536), W = x_proj_w (80x1536)
__global__ __launch_bounds__(256) void sgemm_splitk_xp(
    const float* __restrict__ A, const float* __restrict__ W,
    float* __restrict__ part)
{
  __shared__ float As[16][64];
  __shared__ float Wsh[16][64];
  const int bm = blockIdx.y*64, bn = blockIdx.x*64;
  const int s = blockIdx.z;
  const int koff = s*XKC;
  const int tid = threadIdx.x;
  const int tx = tid & 15, ty = tid >> 4;
  const int lm = tid & 63, lk = (tid >> 6) << 2;
  float acc[4][4] = {};
  const float* Ap = A + (size_t)(bm+lm)*D_INNER + koff + lk;
  const float* Wp = W + (size_t)(bn+lm)*D_INNER + koff + lk;
  const bool wok = (bn+lm) < XP_N;
  for (int k0 = 0; k0 < XKC; k0 += 16){
    float4 av = *(const float4*)(Ap + k0);
    float4 wv = wok ? *(const float4*)(Wp + k0) : make_float4(0.f,0.f,0.f,0.f);
    As[lk+0][lm]=av.x; As[lk+1][lm]=av.y; As[lk+2][lm]=av.z; As[lk+3][lm]=av.w;
    Wsh[lk+0][lm]=wv.x; Wsh[lk+1][lm]=wv.y; Wsh[lk+2][lm]=wv.z; Wsh[lk+3][lm]=wv.w;
    __syncthreads();
    #pragma unroll
    for (int k = 0; k < 16; k++){
      float a[4], w[4];
      #pragma unroll
      for (int i=0;i<4;i++) a[i] = As[k][ty*4+i];
      #pragma unroll
      for (int j=0;j<4;j++) w[j] = Wsh[k][tx*4+j];
      #pragma unroll
      for (int i=0;i<4;i++)
        #pragma unroll
        for (int j=0;j<4;j++)
          acc[i][j] += a[i]*w[j];
    }
    __syncthreads();
  }
  #pragma unroll
  for (int i=0;i<4;i++){
    const int r = bm + ty*4 + i;
    #pragma unroll
    for (int j=0;j<4;j++){
      const int n = bn + tx*4 + j;
      if (n < XP_N)
        part[((size_t)s*ROWS + r)*XP_N + n] = acc[i][j];
    }
  }
}

__global__ __launch_bounds__(256) void reduce_xp(const float* __restrict__ part,
                                                 float* __restrict__ xp){
  const int i = blockIdx.x*256 + threadIdx.x;
  if (i >= ROWS*XP_N) return;
  float s = 0.f;
  #pragma unroll
  for (int c=0;c<XS;c++) s += part[(size_t)c*ROWS*XP_N + i];
  xp[i] = s;
}

// ---------------- residual add + RMSNorm (bf16 or fp32 out) ----------------
__global__ __launch_bounds__(256) void add_rmsnorm(
    float* __restrict__ resid, const float* __restrict__ add,
    const float* __restrict__ w, float* __restrict__ out,
    unsigned short* __restrict__ obf)
{
  const int row = blockIdx.x;
  const int tid = threadIdx.x;
  float v[3];
  float ss = 0.f;
  #pragma unroll
  for (int i=0;i<3;i++){
    const int c = tid + i*256;
    float r = resid[(size_t)row*768 + c];
    if (add) r += add[(size_t)row*768 + c];
    v[i] = r;
    ss += r*r;
  }
  #pragma unroll
  for (int off=32; off>=1; off>>=1) ss += __shfl_xor(ss, off);
  __shared__ float sred[4];
  const int lane = tid & 63, wv = tid >> 6;
  if (lane == 0) sred[wv] = ss;
  __syncthreads();
  const float tot = sred[0]+sred[1]+sred[2]+sred[3];
  const float scale = rsqrtf(tot*(1.0f/768.0f) + 1e-5f);
  #pragma unroll
  for (int i=0;i<3;i++){
    const int c = tid + i*256;
    if (add) resid[(size_t)row*768 + c] = v[i];
    const float o = v[i]*scale*w[c];
    if (obf) obf[(size_t)row*768 + c] = f2bf(o);
    else     out[(size_t)row*768 + c] = o;
  }
}

// ---------------- causal depthwise conv (K=4) + silu ----------------
__global__ __launch_bounds__(256) void conv_silu(
    const float* __restrict__ xz, const float* __restrict__ cw,
    const float* __restrict__ cb, float* __restrict__ uo)
{
  const int idx = blockIdx.x*256 + threadIdx.x;
  if (idx >= ROWS*D_INNER) return;
  const int d = idx % D_INNER;
  const int row = idx / D_INNER;
  const int t = row & (T_SZ-1);
  float acc = cb[d];
  #pragma unroll
  for (int k=0;k<4;k++){
    const int tt = t - 3 + k;
    if (tt >= 0)
      acc += xz[(size_t)(row - 3 + k)*3072 + d] * cw[d*4 + k];
  }
  uo[idx] = siluf_(acc);
}

// ---------------- chunked selective scan: lane = (b,c,d), 16 n-states in regs ----------------
// Pass 1: local scan from h=0; emit P = prod(dA), h_end. grid (6, B, CH-1).
__global__ __launch_bounds__(256) void scan_pass1(
    const float* __restrict__ delta, const float* __restrict__ u,
    const float* __restrict__ xp, const float* __restrict__ alog,
    float* __restrict__ Pend, float* __restrict__ Hend)
{
  const int d = blockIdx.x*256 + threadIdx.x;
  const int b = blockIdx.y, c = blockIdx.z;
  float4 t0 = *(const float4*)(alog + d*16 + 0);
  float4 t1 = *(const float4*)(alog + d*16 + 4);
  float4 t2 = *(const float4*)(alog + d*16 + 8);
  float4 t3 = *(const float4*)(alog + d*16 + 12);
  float Av[16] = {t0.x,t0.y,t0.z,t0.w,t1.x,t1.y,t1.z,t1.w,
                  t2.x,t2.y,t2.z,t2.w,t3.x,t3.y,t3.z,t3.w};
  float h[16], P[16];
  #pragma unroll
  for (int n=0;n<16;n++){ Av[n] = -__expf(Av[n]); h[n]=0.f; P[n]=1.f; }
  const size_t row0 = (size_t)b*T_SZ + (size_t)c*CT;
  const float* dp = delta + row0*D_INNER + d;
  const float* up = u     + row0*D_INNER + d;
  const float* bp = xp    + row0*XP_N + 48;
  for (int t=0;t<CT;t++){
    const float dv = dp[(size_t)t*D_INNER];
    const float uv = up[(size_t)t*D_INNER];
    const float4 B0 = *(const float4*)(bp + (size_t)t*XP_N);
    const float4 B1 = *(const float4*)(bp + (size_t)t*XP_N + 4);
    const float4 B2 = *(const float4*)(bp + (size_t)t*XP_N + 8);
    const float4 B3 = *(const float4*)(bp + (size_t)t*XP_N + 12);
    const float Bv[16] = {B0.x,B0.y,B0.z,B0.w,B1.x,B1.y,B1.z,B1.w,
                          B2.x,B2.y,B2.z,B2.w,B3.x,B3.y,B3.z,B3.w};
    const float du = dv*uv;
    #pragma unroll
    for (int n=0;n<16;n++){
      const float dA = __expf(dv*Av[n]);
      P[n] *= dA;
      h[n] = dA*h[n] + du*Bv[n];
    }
  }
  float* Pp = Pend + ((size_t)(b*CH+c)*D_INNER + d)*16;
  float* Hp = Hend + ((size_t)(b*CH+c)*D_INNER + d)*16;
  *(float4*)(Pp+ 0) = make_float4(P[0],P[1],P[2],P[3]);
  *(float4*)(Pp+ 4) = make_float4(P[4],P[5],P[6],P[7]);
  *(float4*)(Pp+ 8) = make_float4(P[8],P[9],P[10],P[11]);
  *(float4*)(Pp+12) = make_float4(P[12],P[13],P[14],P[15]);
  *(float4*)(Hp+ 0) = make_float4(h[0],h[1],h[2],h[3]);
  *(float4*)(Hp+ 4) = make_float4(h[4],h[5],h[6],h[7]);
  *(float4*)(Hp+ 8) = make_float4(h[8],h[9],h[10],h[11]);
  *(float4*)(Hp+12) = make_float4(h[12],h[13],h[14],h[15]);
}

// Pass 2: sequential combine over chunks (parallel over 98304 (b,d,n) states).
__global__ __launch_bounds__(256) void scan_combine(
    const float* __restrict__ Pend, const float* __restrict__ Hend,
    float* __restrict__ Hin)
{
  const int gid = blockIdx.x*256 + threadIdx.x;       // 0..98303
  const int b = gid / (D_INNER*16);
  const int r = gid % (D_INNER*16);
  const size_t base = (size_t)b*CH*D_INNER*16 + r;
  const size_t step = (size_t)D_INNER*16;
  float h = 0.f;
  Hin[base] = 0.f;
  for (int c=0; c<CH-1; c++){
    h = Pend[base + (size_t)c*step]*h + Hend[base + (size_t)c*step];
    Hin[base + (size_t)(c+1)*step] = h;
  }
}

// Pass 3: re-run chunk with correct h0, emit y (bf16). grid (6, B, CH).
__global__ __launch_bounds__(256) void scan_pass3(
    const float* __restrict__ delta, const float* __restrict__ u,
    const float* __restrict__ xp, const float* __restrict__ xz,
    const float* __restrict__ alog, const float* __restrict__ Dp,
    const float* __restrict__ Hin, unsigned short* __restrict__ yb)
{
  const int d = blockIdx.x*256 + threadIdx.x;
  const int b = blockIdx.y, c = blockIdx.z;
  float4 t0 = *(const float4*)(alog + d*16 + 0);
  float4 t1 = *(const float4*)(alog + d*16 + 4);
  float4 t2 = *(const float4*)(alog + d*16 + 8);
  float4 t3 = *(const float4*)(alog + d*16 + 12);
  float Av[16] = {t0.x,t0.y,t0.z,t0.w,t1.x,t1.y,t1.z,t1.w,
                  t2.x,t2.y,t2.z,t2.w,t3.x,t3.y,t3.z,t3.w};
  #pragma unroll
  for (int n=0;n<16;n++) Av[n] = -__expf(Av[n]);
  const float* Hp = Hin + ((size_t)(b*CH+c)*D_INNER + d)*16;
  float4 h0 = *(const float4*)(Hp+0);
  float4 h1 = *(const float4*)(Hp+4);
  float4 h2 = *(const float4*)(Hp+8);
  float4 h3 = *(const float4*)(Hp+12);
  float h[16] = {h0.x,h0.y,h0.z,h0.w,h1.x,h1.y,h1.z,h1.w,
                 h2.x,h2.y,h2.z,h2.w,h3.x,h3.y,h3.z,h3.w};
  const float Dv = Dp[d];
  const size_t row0 = (size_t)b*T_SZ + (size_t)c*CT;
  const float* dp = delta + row0*D_INNER + d;
  const float* up = u     + row0*D_INNER + d;
  const float* bp = xp    + row0*XP_N + 48;
  const float* cp = xp    + row0*XP_N + 64;
  const float* zp = xz    + row0*3072 + 1536 + d;
  unsigned short* yp = yb + row0*D_INNER + d;
  for (int t=0;t<CT;t++){
    const float dv = dp[(size_t)t*D_INNER];
    const float uv = up[(size_t)t*D_INNER];
    const float zv = zp[(size_t)t*3072];
    const float4 B0 = *(const float4*)(bp + (size_t)t*XP_N);
    const float4 B1 = *(const float4*)(bp + (size_t)t*XP_N + 4);
    const float4 B2 = *(const float4*)(bp + (size_t)t*XP_N + 8);
    const float4 B3 = *(const float4*)(bp + (size_t)t*XP_N + 12);
    const float4 C0 = *(const float4*)(cp + (size_t)t*XP_N);
    const float4 C1 = *(const float4*)(cp + (size_t)t*XP_N + 4);
    const float4 C2 = *(const float4*)(cp + (size_t)t*XP_N + 8);
    const float4 C3 = *(const float4*)(cp + (size_t)t*XP_N + 12);
    const float Bv[16] = {B0.x,B0.y,B0.z,B0.w,B1.x,B1.y,B1.z,B1.w,
                          B2.x,B2.y,B2.z,B2.w,B3.x,B3.y,B3.z,B3.w};
    const float Cv[16] = {C0.x,C0.y,C0.z,C0.w,C1.x,C1.y,C1.z,C1.w,
                          C2.x,C2.y,C2.z,C2.w,C3.x,C3.y,C3.z,C3.w};
    const float du = dv*uv;
    float p = 0.f;
    #pragma unroll
    for (int n=0;n<16;n++){
      const float dA = __expf(dv*Av[n]);
      h[n] = dA*h[n] + du*Bv[n];
      p += h[n]*Cv[n];
    }
    yp[(size_t)t*D_INNER] = f2bf((p + uv*Dv)*siluf_(zv));
  }
}

// ---------------- mean pool over T ----------------
__global__ void pool_mean(const float* __restrict__ normed, float* __restrict__ pooled){
  const int idx = blockIdx.x*256 + threadIdx.x;
  if (idx >= B_SZ*768) return;
  const int b = idx / 768, m = idx % 768;
  float s = 0.f;
  for (int t=0; t<T_SZ; t++) s += normed[((size_t)b*T_SZ + t)*768 + m];
  pooled[idx] = s * (1.0f/T_SZ);
}

// ---------------- classifier head: out (4,10) ----------------
__global__ void cls_head(const float* __restrict__ pooled, const float* __restrict__ cw,
                         const float* __restrict__ cb, float* __restrict__ out){
  const int o = blockIdx.x % 10, b = blockIdx.x / 10;
  const int lane = threadIdx.x; // 64
  float s = 0.f;
  for (int k = lane; k < 768; k += 64) s += pooled[b*768 + k]*cw[o*768 + k];
  #pragma unroll
  for (int off=32; off>=1; off>>=1) s += __shfl_xor(s, off);
  if (lane == 0) out[b*10 + o] = s + cb[o];
}

extern "C" void kernel_launch(void* const* d_in, const int* in_sizes, int n_in,
                              void* d_out, int out_size, void* d_ws, size_t ws_size,
                              hipStream_t stream) {
  const float* x         = (const float*)d_in[0];
  const float* in_proj_w = (const float*)d_in[1];
  const float* conv_w    = (const float*)d_in[2];
  const float* conv_b    = (const float*)d_in[3];
  const float* x_proj_w  = (const float*)d_in[4];
  const float* dt_proj_w = (const float*)d_in[5];
  const float* dt_proj_b = (const float*)d_in[6];
  const float* A_log     = (const float*)d_in[7];
  const float* D_param   = (const float*)d_in[8];
  const float* out_proj_w= (const float*)d_in[9];
  const float* norm_w    = (const float*)d_in[10];
  const float* norm_f_w  = (const float*)d_in[11];
  const float* inp_w     = (const float*)d_in[12];
  const float* inp_b     = (const float*)d_in[13];
  const float* cls_w     = (const float*)d_in[14];
  const float* cls_b     = (const float*)d_in[15];
  float* out = (float*)d_out;

  char* ws = (char*)d_ws;
  auto carve = [&](size_t nelem)->float* {
    float* p = (float*)ws;
    ws += ((nelem*sizeof(float) + 255)/256)*256;
    return p;
  };
  float* xt     = carve((size_t)ROWS*256);
  float* resid  = carve((size_t)ROWS*768);
  float* normed = carve((size_t)ROWS*768);   // bf16 normed (lower half) / Pend during scan / fp32 at final
  float* hidden = carve((size_t)ROWS*768);   // Hend during scan
  float* xz     = carve((size_t)ROWS*3072);
  float* ucv    = carve((size_t)ROWS*1536);
  float* xp     = carve((size_t)ROWS*XP_N);
  float* delta  = carve((size_t)ROWS*1536);
  float* ybf_f  = carve((size_t)ROWS*1536/2);     // bf16 y
  float* wbf_f  = carve((size_t)(3072*768)/2);    // per-layer bf16 weights
  float* Hin    = carve((size_t)B_SZ*CH*D_INNER*16);   // 1.57M floats
  float* xpart  = carve((size_t)XS*ROWS*XP_N);         // 1.31M floats
  float* pooled = carve((size_t)B_SZ*768);

  unsigned short* normedb = (unsigned short*)normed;
  unsigned short* ybf = (unsigned short*)ybf_f;
  unsigned short* wbf = (unsigned short*)wbf_f;
  float* Pend = normed;    // 1,572,864 floats — exact fit, dead during scan
  float* Hend = hidden;    // 1,572,864 floats — exact fit, dead during scan

  transpose_x<<<dim3(16,8,4), dim3(32,32), 0, stream>>>(x, xt);
  sgemm_tn<<<dim3(12,32), 256, 0, stream>>>(xt, 256, inp_w, inp_b, resid, ROWS, 768, 256, 0);

  for (int l = 0; l < 4; l++){
    add_rmsnorm<<<ROWS, 256, 0, stream>>>(resid, l ? hidden : nullptr, norm_w + (size_t)l*768,
                                          nullptr, normedb);
    cast_bf16<<<(3072*768)/1024, 256, 0, stream>>>(in_proj_w + (size_t)l*3072*768, wbf, 3072*768);
    gemm_bf16<<<dim3(24,16), 256, 0, stream>>>(normedb, wbf, xz, ROWS, 3072, 768);
    conv_silu<<<(ROWS*D_INNER)/256, 256, 0, stream>>>(xz, conv_w + (size_t)l*1536*4, conv_b + (size_t)l*1536, ucv);
    sgemm_splitk_xp<<<dim3(2,32,XS), 256, 0, stream>>>(ucv, x_proj_w + (size_t)l*XP_N*1536, xpart);
    reduce_xp<<<(ROWS*XP_N)/256, 256, 0, stream>>>(xpart, xp);
    sgemm_tn<<<dim3(24,32), 256, 0, stream>>>(xp, XP_N, dt_proj_w + (size_t)l*1536*48, dt_proj_b + (size_t)l*1536,
                                              delta, ROWS, 1536, 48, 1);
    scan_pass1<<<dim3(6,B_SZ,CH-1), 256, 0, stream>>>(delta, ucv, xp,
                                               A_log + (size_t)l*1536*16, Pend, Hend);
    scan_combine<<<(B_SZ*D_INNER*16)/256, 256, 0, stream>>>(Pend, Hend, Hin);
    scan_pass3<<<dim3(6,B_SZ,CH), 256, 0, stream>>>(delta, ucv, xp, xz,
                                               A_log + (size_t)l*1536*16, D_param + (size_t)l*1536, Hin, ybf);
    cast_bf16<<<(768*1536)/1024, 256, 0, stream>>>(out_proj_w + (size_t)l*768*1536, wbf, 768*1536);
    gemm_bf16<<<dim3(6,16), 256, 0, stream>>>(ybf, wbf, hidden, ROWS, 768, 1536);
  }

  add_rmsnorm<<<ROWS, 256, 0, stream>>>(resid, hidden, norm_f_w, normed, nullptr);
  pool_mean<<<12, 256, 0, stream>>>(normed, pooled);
  cls_head<<<40, 64, 0, stream>>>(pooled, cls_w, cls_b, out);
}

// Round 5
// 848.968 us; speedup vs baseline: 3.8523x; 1.1490x over previous
//
#include <hip/hip_runtime.h>
#include <math.h>

#define D_MODEL 768
#define D_INNER 1536
#define B_SZ 4
#define T_SZ 512
#define ROWS (B_SZ*T_SZ)   // 2048
#define XP_N 80
#define CH 16              // scan chunks
#define CT 32              // T per chunk
#define XS 8               // x_proj split-K factor
#define XKC (D_INNER/XS)   // 192
#define OS 4               // out_proj split-K factor
#define OKC (D_INNER/OS)   // 384
#define MN_OUT (ROWS*768)  // 1572864

typedef __attribute__((ext_vector_type(8))) short bf16x8;
typedef __attribute__((ext_vector_type(4))) float f32x4;

__device__ __forceinline__ float sigmoidf_(float x){ return 1.0f/(1.0f+__expf(-x)); }
__device__ __forceinline__ float siluf_(float x){ return x*sigmoidf_(x); }
__device__ __forceinline__ unsigned short f2bf(float f){
  unsigned u = __builtin_bit_cast(unsigned, f);
  u = (u + 0x7FFFu + ((u >> 16) & 1u)) >> 16;   // RNE
  return (unsigned short)u;
}

// ---------------- transpose: x (B,256,512) -> xt (B,512,256) ----------------
__global__ void transpose_x(const float* __restrict__ x, float* __restrict__ xt){
  __shared__ float s[32][33];
  int b = blockIdx.z;
  int t0 = blockIdx.x*32, c0 = blockIdx.y*32;
  int tx = threadIdx.x, ty = threadIdx.y;
  s[ty][tx] = x[((size_t)b*256 + (c0+ty))*512 + (t0+tx)];
  __syncthreads();
  xt[((size_t)b*512 + (t0+ty))*256 + (c0+tx)] = s[tx][ty];
}

// ---------------- fused fp32->bf16 cast of both per-layer weight mats ----------------
// blocks [0, nb1) cast in1 (n1 elems); blocks [nb1, nb1+nb2) cast in2 (n2 elems)
__global__ __launch_bounds__(256) void cast2_bf16(
    const float* __restrict__ in1, unsigned short* __restrict__ o1, int n1, int nb1,
    const float* __restrict__ in2, unsigned short* __restrict__ o2, int n2)
{
  const float* in; unsigned short* o; int i4;
  if ((int)blockIdx.x < nb1){ in = in1; o = o1; i4 = (blockIdx.x*256 + threadIdx.x)*4; if (i4 >= n1) return; }
  else { in = in2; o = o2; i4 = ((blockIdx.x-nb1)*256 + threadIdx.x)*4; if (i4 >= n2) return; }
  float4 v = *(const float4*)(in + i4);
  ushort4 r;
  r.x = f2bf(v.x); r.y = f2bf(v.y); r.z = f2bf(v.z); r.w = f2bf(v.w);
  *(ushort4*)(o + i4) = r;
}

// ---------------- bf16 MFMA GEMM: C[M,N] = A[M,K] * W[N,K]^T ----------------
// Requires M%128==0, N%128==0, K%32==0. 256 threads = 4 waves (2x2 of 64x64).
#define LDP 40
__global__ __launch_bounds__(256) void gemm_bf16(
    const unsigned short* __restrict__ A, const unsigned short* __restrict__ Wb,
    float* __restrict__ C, int M, int N, int K)
{
  __shared__ unsigned short As[128*LDP];
  __shared__ unsigned short Ws[128*LDP];
  const int tid = threadIdx.x;
  const int bm = blockIdx.y*128, bn = blockIdx.x*128;
  const int wave = tid >> 6, lane = tid & 63;
  const int wm = (wave >> 1)*64, wn = (wave & 1)*64;
  const int fr = lane & 15, quad = lane >> 4;
  f32x4 acc[4][4] = {};
  const int srow = tid >> 1, scol = (tid & 1)*16;
  const unsigned short* Ag = A  + (size_t)(bm + srow)*K + scol;
  const unsigned short* Wg = Wb + (size_t)(bn + srow)*K + scol;
  unsigned short* Asw = As + srow*LDP + scol;
  unsigned short* Wsw = Ws + srow*LDP + scol;

  for (int k0 = 0; k0 < K; k0 += 32){
    float4 av0 = *(const float4*)(Ag + k0);
    float4 av1 = *(const float4*)(Ag + k0 + 8);
    float4 wv0 = *(const float4*)(Wg + k0);
    float4 wv1 = *(const float4*)(Wg + k0 + 8);
    __syncthreads();
    *(float4*)(Asw)     = av0; *(float4*)(Asw + 8) = av1;
    *(float4*)(Wsw)     = wv0; *(float4*)(Wsw + 8) = wv1;
    __syncthreads();
    bf16x8 a[4], b[4];
    #pragma unroll
    for (int i=0;i<4;i++)
      a[i] = *(const bf16x8*)(As + (wm + i*16 + fr)*LDP + quad*8);
    #pragma unroll
    for (int j=0;j<4;j++)
      b[j] = *(const bf16x8*)(Ws + (wn + j*16 + fr)*LDP + quad*8);
    #pragma unroll
    for (int i=0;i<4;i++)
      #pragma unroll
      for (int j=0;j<4;j++)
        acc[i][j] = __builtin_amdgcn_mfma_f32_16x16x32_bf16(a[i], b[j], acc[i][j], 0, 0, 0);
  }
  #pragma unroll
  for (int i=0;i<4;i++){
    #pragma unroll
    for (int r=0;r<4;r++){
      const int row = bm + wm + i*16 + quad*4 + r;
      float* Cp = C + (size_t)row*N + bn + wn + fr;
      #pragma unroll
      for (int j=0;j<4;j++)
        Cp[j*16] = acc[i][j][r];
    }
  }
}

// ---------------- bf16 MFMA GEMM, split-K: partials for out_proj ----------------
// grid (N/128, M/128, OS); partial s lives in (s<2 ? P0 : P1) + (s&1)*MN_OUT
__global__ __launch_bounds__(256) void gemm_bf16_sk(
    const unsigned short* __restrict__ A, const unsigned short* __restrict__ Wb,
    float* __restrict__ P0, float* __restrict__ P1, int M, int N, int K)
{
  __shared__ unsigned short As[128*LDP];
  __shared__ unsigned short Ws[128*LDP];
  const int tid = threadIdx.x;
  const int bm = blockIdx.y*128, bn = blockIdx.x*128;
  const int s = blockIdx.z;
  const int koff = s*OKC;
  const int wave = tid >> 6, lane = tid & 63;
  const int wm = (wave >> 1)*64, wn = (wave & 1)*64;
  const int fr = lane & 15, quad = lane >> 4;
  f32x4 acc[4][4] = {};
  const int srow = tid >> 1, scol = (tid & 1)*16;
  const unsigned short* Ag = A  + (size_t)(bm + srow)*K + koff + scol;
  const unsigned short* Wg = Wb + (size_t)(bn + srow)*K + koff + scol;
  unsigned short* Asw = As + srow*LDP + scol;
  unsigned short* Wsw = Ws + srow*LDP + scol;

  for (int k0 = 0; k0 < OKC; k0 += 32){
    float4 av0 = *(const float4*)(Ag + k0);
    float4 av1 = *(const float4*)(Ag + k0 + 8);
    float4 wv0 = *(const float4*)(Wg + k0);
    float4 wv1 = *(const float4*)(Wg + k0 + 8);
    __syncthreads();
    *(float4*)(Asw)     = av0; *(float4*)(Asw + 8) = av1;
    *(float4*)(Wsw)     = wv0; *(float4*)(Wsw + 8) = wv1;
    __syncthreads();
    bf16x8 a[4], b[4];
    #pragma unroll
    for (int i=0;i<4;i++)
      a[i] = *(const bf16x8*)(As + (wm + i*16 + fr)*LDP + quad*8);
    #pragma unroll
    for (int j=0;j<4;j++)
      b[j] = *(const bf16x8*)(Ws + (wn + j*16 + fr)*LDP + quad*8);
    #pragma unroll
    for (int i=0;i<4;i++)
      #pragma unroll
      for (int j=0;j<4;j++)
        acc[i][j] = __builtin_amdgcn_mfma_f32_16x16x32_bf16(a[i], b[j], acc[i][j], 0, 0, 0);
  }
  float* Cb = (s < 2 ? P0 : P1) + (size_t)(s & 1)*MN_OUT;
  #pragma unroll
  for (int i=0;i<4;i++){
    #pragma unroll
    for (int r=0;r<4;r++){
      const int row = bm + wm + i*16 + quad*4 + r;
      float* Cp = Cb + (size_t)row*N + bn + wn + fr;
      #pragma unroll
      for (int j=0;j<4;j++)
        Cp[j*16] = acc[i][j][r];
    }
  }
}

__global__ __launch_bounds__(256) void reduce_out(
    const float* __restrict__ P0, const float* __restrict__ P1,
    float* __restrict__ C)
{
  const int i = blockIdx.x*256 + threadIdx.x;
  C[i] = (P0[i] + P0[MN_OUT + i]) + (P1[i] + P1[MN_OUT + i]);
}

// ---------------- fp32 SGEMM (dt_proj / input) ----------------
__global__ __launch_bounds__(256) void sgemm_tn(
    const float* __restrict__ A, int lda,
    const float* __restrict__ W,
    const float* __restrict__ bias,
    float* __restrict__ C, int M, int N, int K, int act)
{
  __shared__ float As[16][64];
  __shared__ float Wsh[16][64];
  const int bm = blockIdx.y*64, bn = blockIdx.x*64;
  const int tid = threadIdx.x;
  const int tx = tid & 15, ty = tid >> 4;
  const int lm = tid & 63, lk = (tid >> 6) << 2;
  float acc[4][4] = {};
  const float* Ap = A + (size_t)(bm+lm)*lda + lk;
  const float* Wp = W + (size_t)(bn+lm)*K + lk;
  const bool wok = (bn+lm) < N;
  for (int k0 = 0; k0 < K; k0 += 16){
    float4 av = *(const float4*)(Ap + k0);
    float4 wv = wok ? *(const float4*)(Wp + k0) : make_float4(0.f,0.f,0.f,0.f);
    As[lk+0][lm]=av.x; As[lk+1][lm]=av.y; As[lk+2][lm]=av.z; As[lk+3][lm]=av.w;
    Wsh[lk+0][lm]=wv.x; Wsh[lk+1][lm]=wv.y; Wsh[lk+2][lm]=wv.z; Wsh[lk+3][lm]=wv.w;
    __syncthreads();
    #pragma unroll
    for (int k = 0; k < 16; k++){
      float a[4], w[4];
      #pragma unroll
      for (int i=0;i<4;i++) a[i] = As[k][ty*4+i];
      #pragma unroll
      for (int j=0;j<4;j++) w[j] = Wsh[k][tx*4+j];
      #pragma unroll
      for (int i=0;i<4;i++)
        #pragma unroll
        for (int j=0;j<4;j++)
          acc[i][j] += a[i]*w[j];
    }
    __syncthreads();
  }
  #pragma unroll
  for (int i=0;i<4;i++){
    const int r = bm + ty*4 + i;
    #pragma unroll
    for (int j=0;j<4;j++){
      const int n = bn + tx*4 + j;
      if (n < N){
        float v = acc[i][j] + (bias ? bias[n] : 0.f);
        if (act == 1){ v = (v > 20.f) ? v : log1pf(__expf(v)); }
        C[(size_t)r*N + n] = v;
      }
    }
  }
}

// ---------------- x_proj split-K fp32 ----------------
__global__ __launch_bounds__(256) void sgemm_splitk_xp(
    const float* __restrict__ A, const float* __restrict__ W,
    float* __restrict__ part)
{
  __shared__ float As[16][64];
  __shared__ float Wsh[16][64];
  const int bm = blockIdx.y*64, bn = blockIdx.x*64;
  const int s = blockIdx.z;
  const int koff = s*XKC;
  const int tid = threadIdx.x;
  const int tx = tid & 15, ty = tid >> 4;
  const int lm = tid & 63, lk = (tid >> 6) << 2;
  float acc[4][4] = {};
  const float* Ap = A + (size_t)(bm+lm)*D_INNER + koff + lk;
  const float* Wp = W + (size_t)(bn+lm)*D_INNER + koff + lk;
  const bool wok = (bn+lm) < XP_N;
  for (int k0 = 0; k0 < XKC; k0 += 16){
    float4 av = *(const float4*)(Ap + k0);
    float4 wv = wok ? *(const float4*)(Wp + k0) : make_float4(0.f,0.f,0.f,0.f);
    As[lk+0][lm]=av.x; As[lk+1][lm]=av.y; As[lk+2][lm]=av.z; As[lk+3][lm]=av.w;
    Wsh[lk+0][lm]=wv.x; Wsh[lk+1][lm]=wv.y; Wsh[lk+2][lm]=wv.z; Wsh[lk+3][lm]=wv.w;
    __syncthreads();
    #pragma unroll
    for (int k = 0; k < 16; k++){
      float a[4], w[4];
      #pragma unroll
      for (int i=0;i<4;i++) a[i] = As[k][ty*4+i];
      #pragma unroll
      for (int j=0;j<4;j++) w[j] = Wsh[k][tx*4+j];
      #pragma unroll
      for (int i=0;i<4;i++)
        #pragma unroll
        for (int j=0;j<4;j++)
          acc[i][j] += a[i]*w[j];
    }
    __syncthreads();
  }
  #pragma unroll
  for (int i=0;i<4;i++){
    const int r = bm + ty*4 + i;
    #pragma unroll
    for (int j=0;j<4;j++){
      const int n = bn + tx*4 + j;
      if (n < XP_N)
        part[((size_t)s*ROWS + r)*XP_N + n] = acc[i][j];
    }
  }
}

__global__ __launch_bounds__(256) void reduce_xp(const float* __restrict__ part,
                                                 float* __restrict__ xp){
  const int i = blockIdx.x*256 + threadIdx.x;
  if (i >= ROWS*XP_N) return;
  float s = 0.f;
  #pragma unroll
  for (int c=0;c<XS;c++) s += part[(size_t)c*ROWS*XP_N + i];
  xp[i] = s;
}

// ---------------- residual add + RMSNorm (bf16 or fp32 out) ----------------
__global__ __launch_bounds__(256) void add_rmsnorm(
    float* __restrict__ resid, const float* __restrict__ add,
    const float* __restrict__ w, float* __restrict__ out,
    unsigned short* __restrict__ obf)
{
  const int row = blockIdx.x;
  const int tid = threadIdx.x;
  float v[3];
  float ss = 0.f;
  #pragma unroll
  for (int i=0;i<3;i++){
    const int c = tid + i*256;
    float r = resid[(size_t)row*768 + c];
    if (add) r += add[(size_t)row*768 + c];
    v[i] = r;
    ss += r*r;
  }
  #pragma unroll
  for (int off=32; off>=1; off>>=1) ss += __shfl_xor(ss, off);
  __shared__ float sred[4];
  const int lane = tid & 63, wv = tid >> 6;
  if (lane == 0) sred[wv] = ss;
  __syncthreads();
  const float tot = sred[0]+sred[1]+sred[2]+sred[3];
  const float scale = rsqrtf(tot*(1.0f/768.0f) + 1e-5f);
  #pragma unroll
  for (int i=0;i<3;i++){
    const int c = tid + i*256;
    if (add) resid[(size_t)row*768 + c] = v[i];
    const float o = v[i]*scale*w[c];
    if (obf) obf[(size_t)row*768 + c] = f2bf(o);
    else     out[(size_t)row*768 + c] = o;
  }
}

// ---------------- causal depthwise conv (K=4) + silu ----------------
__global__ __launch_bounds__(256) void conv_silu(
    const float* __restrict__ xz, const float* __restrict__ cw,
    const float* __restrict__ cb, float* __restrict__ uo)
{
  const int idx = blockIdx.x*256 + threadIdx.x;
  if (idx >= ROWS*D_INNER) return;
  const int d = idx % D_INNER;
  const int row = idx / D_INNER;
  const int t = row & (T_SZ-1);
  float acc = cb[d];
  #pragma unroll
  for (int k=0;k<4;k++){
    const int tt = t - 3 + k;
    if (tt >= 0)
      acc += xz[(size_t)(row - 3 + k)*3072 + d] * cw[d*4 + k];
  }
  uo[idx] = siluf_(acc);
}

// ---------------- chunked selective scan: lane = (b,c,d), 16 n-states in regs ----------------
__global__ __launch_bounds__(256) void scan_pass1(
    const float* __restrict__ delta, const float* __restrict__ u,
    const float* __restrict__ xp, const float* __restrict__ alog,
    float* __restrict__ Pend, float* __restrict__ Hend)
{
  const int d = blockIdx.x*256 + threadIdx.x;
  const int b = blockIdx.y, c = blockIdx.z;
  float4 t0 = *(const float4*)(alog + d*16 + 0);
  float4 t1 = *(const float4*)(alog + d*16 + 4);
  float4 t2 = *(const float4*)(alog + d*16 + 8);
  float4 t3 = *(const float4*)(alog + d*16 + 12);
  float Av[16] = {t0.x,t0.y,t0.z,t0.w,t1.x,t1.y,t1.z,t1.w,
                  t2.x,t2.y,t2.z,t2.w,t3.x,t3.y,t3.z,t3.w};
  float h[16], P[16];
  #pragma unroll
  for (int n=0;n<16;n++){ Av[n] = -__expf(Av[n]); h[n]=0.f; P[n]=1.f; }
  const size_t row0 = (size_t)b*T_SZ + (size_t)c*CT;
  const float* dp = delta + row0*D_INNER + d;
  const float* up = u     + row0*D_INNER + d;
  const float* bp = xp    + row0*XP_N + 48;
  for (int t=0;t<CT;t++){
    const float dv = dp[(size_t)t*D_INNER];
    const float uv = up[(size_t)t*D_INNER];
    const float4 B0 = *(const float4*)(bp + (size_t)t*XP_N);
    const float4 B1 = *(const float4*)(bp + (size_t)t*XP_N + 4);
    const float4 B2 = *(const float4*)(bp + (size_t)t*XP_N + 8);
    const float4 B3 = *(const float4*)(bp + (size_t)t*XP_N + 12);
    const float Bv[16] = {B0.x,B0.y,B0.z,B0.w,B1.x,B1.y,B1.z,B1.w,
                          B2.x,B2.y,B2.z,B2.w,B3.x,B3.y,B3.z,B3.w};
    const float du = dv*uv;
    #pragma unroll
    for (int n=0;n<16;n++){
      const float dA = __expf(dv*Av[n]);
      P[n] *= dA;
      h[n] = dA*h[n] + du*Bv[n];
    }
  }
  float* Pp = Pend + ((size_t)(b*CH+c)*D_INNER + d)*16;
  float* Hp = Hend + ((size_t)(b*CH+c)*D_INNER + d)*16;
  *(float4*)(Pp+ 0) = make_float4(P[0],P[1],P[2],P[3]);
  *(float4*)(Pp+ 4) = make_float4(P[4],P[5],P[6],P[7]);
  *(float4*)(Pp+ 8) = make_float4(P[8],P[9],P[10],P[11]);
  *(float4*)(Pp+12) = make_float4(P[12],P[13],P[14],P[15]);
  *(float4*)(Hp+ 0) = make_float4(h[0],h[1],h[2],h[3]);
  *(float4*)(Hp+ 4) = make_float4(h[4],h[5],h[6],h[7]);
  *(float4*)(Hp+ 8) = make_float4(h[8],h[9],h[10],h[11]);
  *(float4*)(Hp+12) = make_float4(h[12],h[13],h[14],h[15]);
}

__global__ __launch_bounds__(256) void scan_combine(
    const float* __restrict__ Pend, const float* __restrict__ Hend,
    float* __restrict__ Hin)
{
  const int gid = blockIdx.x*256 + threadIdx.x;       // 0..98303
  const int b = gid / (D_INNER*16);
  const int r = gid % (D_INNER*16);
  const size_t base = (size_t)b*CH*D_INNER*16 + r;
  const size_t step = (size_t)D_INNER*16;
  float h = 0.f;
  Hin[base] = 0.f;
  for (int c=0; c<CH-1; c++){
    h = Pend[base + (size_t)c*step]*h + Hend[base + (size_t)c*step];
    Hin[base + (size_t)(c+1)*step] = h;
  }
}

__global__ __launch_bounds__(256) void scan_pass3(
    const float* __restrict__ delta, const float* __restrict__ u,
    const float* __restrict__ xp, const float* __restrict__ xz,
    const float* __restrict__ alog, const float* __restrict__ Dp,
    const float* __restrict__ Hin, unsigned short* __restrict__ yb)
{
  const int d = blockIdx.x*256 + threadIdx.x;
  const int b = blockIdx.y, c = blockIdx.z;
  float4 t0 = *(const float4*)(alog + d*16 + 0);
  float4 t1 = *(const float4*)(alog + d*16 + 4);
  float4 t2 = *(const float4*)(alog + d*16 + 8);
  float4 t3 = *(const float4*)(alog + d*16 + 12);
  float Av[16] = {t0.x,t0.y,t0.z,t0.w,t1.x,t1.y,t1.z,t1.w,
                  t2.x,t2.y,t2.z,t2.w,t3.x,t3.y,t3.z,t3.w};
  #pragma unroll
  for (int n=0;n<16;n++) Av[n] = -__expf(Av[n]);
  const float* Hp = Hin + ((size_t)(b*CH+c)*D_INNER + d)*16;
  float4 h0 = *(const float4*)(Hp+0);
  float4 h1 = *(const float4*)(Hp+4);
  float4 h2 = *(const float4*)(Hp+8);
  float4 h3 = *(const float4*)(Hp+12);
  float h[16] = {h0.x,h0.y,h0.z,h0.w,h1.x,h1.y,h1.z,h1.w,
                 h2.x,h2.y,h2.z,h2.w,h3.x,h3.y,h3.z,h3.w};
  const float Dv = Dp[d];
  const size_t row0 = (size_t)b*T_SZ + (size_t)c*CT;
  const float* dp = delta + row0*D_INNER + d;
  const float* up = u     + row0*D_INNER + d;
  const float* bp = xp    + row0*XP_N + 48;
  const float* cp = xp    + row0*XP_N + 64;
  const float* zp = xz    + row0*3072 + 1536 + d;
  unsigned short* yp = yb + row0*D_INNER + d;
  for (int t=0;t<CT;t++){
    const float dv = dp[(size_t)t*D_INNER];
    const float uv = up[(size_t)t*D_INNER];
    const float zv = zp[(size_t)t*3072];
    const float4 B0 = *(const float4*)(bp + (size_t)t*XP_N);
    const float4 B1 = *(const float4*)(bp + (size_t)t*XP_N + 4);
    const float4 B2 = *(const float4*)(bp + (size_t)t*XP_N + 8);
    const float4 B3 = *(const float4*)(bp + (size_t)t*XP_N + 12);
    const float4 C0 = *(const float4*)(cp + (size_t)t*XP_N);
    const float4 C1 = *(const float4*)(cp + (size_t)t*XP_N + 4);
    const float4 C2 = *(const float4*)(cp + (size_t)t*XP_N + 8);
    const float4 C3 = *(const float4*)(cp + (size_t)t*XP_N + 12);
    const float Bv[16] = {B0.x,B0.y,B0.z,B0.w,B1.x,B1.y,B1.z,B1.w,
                          B2.x,B2.y,B2.z,B2.w,B3.x,B3.y,B3.z,B3.w};
    const float Cv[16] = {C0.x,C0.y,C0.z,C0.w,C1.x,C1.y,C1.z,C1.w,
                          C2.x,C2.y,C2.z,C2.w,C3.x,C3.y,C3.z,C3.w};
    const float du = dv*uv;
    float p = 0.f;
    #pragma unroll
    for (int n=0;n<16;n++){
      const float dA = __expf(dv*Av[n]);
      h[n] = dA*h[n] + du*Bv[n];
      p += h[n]*Cv[n];
    }
    yp[(size_t)t*D_INNER] = f2bf((p + uv*Dv)*siluf_(zv));
  }
}

// ---------------- mean pool, two-stage ----------------
// stage 1: grid (12, 16): block (g,s) sums T-slice [s*32, s*32+32) for 256 (b,m) pairs
__global__ __launch_bounds__(256) void pool_partial(const float* __restrict__ normed,
                                                    float* __restrict__ part){
  const int i = blockIdx.x*256 + threadIdx.x;    // (b,m) flat, 0..3071
  const int s = blockIdx.y;
  const int b = i / 768, m = i % 768;
  float sum = 0.f;
  const float* p = normed + ((size_t)b*T_SZ + s*32)*768 + m;
  #pragma unroll
  for (int t=0; t<32; t++) sum += p[(size_t)t*768];
  part[s*3072 + i] = sum;
}

__global__ void pool_final(const float* __restrict__ part, float* __restrict__ pooled){
  const int i = blockIdx.x*256 + threadIdx.x;   // 0..3071
  if (i >= 3072) return;
  float s = 0.f;
  #pragma unroll
  for (int c=0;c<16;c++) s += part[c*3072 + i];
  pooled[i] = s * (1.0f/T_SZ);
}

// ---------------- classifier head: out (4,10) ----------------
__global__ void cls_head(const float* __restrict__ pooled, const float* __restrict__ cw,
                         const float* __restrict__ cb, float* __restrict__ out){
  const int o = blockIdx.x % 10, b = blockIdx.x / 10;
  const int lane = threadIdx.x; // 64
  float s = 0.f;
  for (int k = lane; k < 768; k += 64) s += pooled[b*768 + k]*cw[o*768 + k];
  #pragma unroll
  for (int off=32; off>=1; off>>=1) s += __shfl_xor(s, off);
  if (lane == 0) out[b*10 + o] = s + cb[o];
}

extern "C" void kernel_launch(void* const* d_in, const int* in_sizes, int n_in,
                              void* d_out, int out_size, void* d_ws, size_t ws_size,
                              hipStream_t stream) {
  const float* x         = (const float*)d_in[0];
  const float* in_proj_w = (const float*)d_in[1];
  const float* conv_w    = (const float*)d_in[2];
  const float* conv_b    = (const float*)d_in[3];
  const float* x_proj_w  = (const float*)d_in[4];
  const float* dt_proj_w = (const float*)d_in[5];
  const float* dt_proj_b = (const float*)d_in[6];
  const float* A_log     = (const float*)d_in[7];
  const float* D_param   = (const float*)d_in[8];
  const float* out_proj_w= (const float*)d_in[9];
  const float* norm_w    = (const float*)d_in[10];
  const float* norm_f_w  = (const float*)d_in[11];
  const float* inp_w     = (const float*)d_in[12];
  const float* inp_b     = (const float*)d_in[13];
  const float* cls_w     = (const float*)d_in[14];
  const float* cls_b     = (const float*)d_in[15];
  float* out = (float*)d_out;

  char* ws = (char*)d_ws;
  auto carve = [&](size_t nelem)->float* {
    float* p = (float*)ws;
    ws += ((nelem*sizeof(float) + 255)/256)*256;
    return p;
  };
  float* xt     = carve((size_t)ROWS*256);
  float* resid  = carve((size_t)ROWS*768);
  float* normed = carve((size_t)ROWS*768);   // bf16 normed (lower) / Pend during scan / fp32 at final
  float* hidden = carve((size_t)ROWS*768);   // Hend during scan
  float* xz     = carve((size_t)ROWS*3072);
  float* ucv    = carve((size_t)ROWS*1536);  // out_proj partials s=2,3 after scan
  float* xp     = carve((size_t)ROWS*XP_N);
  float* delta  = carve((size_t)ROWS*1536);  // out_proj partials s=0,1 after scan
  float* ybf_f  = carve((size_t)ROWS*1536/2);     // bf16 y
  float* wbi_f  = carve((size_t)(3072*768)/2);    // per-layer bf16 in_proj w
  float* wbo_f  = carve((size_t)(768*1536)/2);    // per-layer bf16 out_proj w
  float* Hin    = carve((size_t)B_SZ*CH*D_INNER*16);   // 1.57M floats
  float* xpart  = carve((size_t)XS*ROWS*XP_N);         // 1.31M floats
  float* ppool  = carve((size_t)16*3072);
  float* pooled = carve((size_t)B_SZ*768);

  unsigned short* normedb = (unsigned short*)normed;
  unsigned short* ybf = (unsigned short*)ybf_f;
  unsigned short* wbi = (unsigned short*)wbi_f;
  unsigned short* wbo = (unsigned short*)wbo_f;
  float* Pend = normed;    // dead during scan
  float* Hend = hidden;    // dead during scan

  transpose_x<<<dim3(16,8,4), dim3(32,32), 0, stream>>>(x, xt);
  sgemm_tn<<<dim3(12,32), 256, 0, stream>>>(xt, 256, inp_w, inp_b, resid, ROWS, 768, 256, 0);

  for (int l = 0; l < 4; l++){
    add_rmsnorm<<<ROWS, 256, 0, stream>>>(resid, l ? hidden : nullptr, norm_w + (size_t)l*768,
                                          nullptr, normedb);
    // cast both weight mats in one launch: 2304 + 1152 blocks
    cast2_bf16<<<2304+1152, 256, 0, stream>>>(in_proj_w + (size_t)l*3072*768, wbi, 3072*768, 2304,
                                              out_proj_w + (size_t)l*768*1536, wbo, 768*1536);
    gemm_bf16<<<dim3(24,16), 256, 0, stream>>>(normedb, wbi, xz, ROWS, 3072, 768);
    conv_silu<<<(ROWS*D_INNER)/256, 256, 0, stream>>>(xz, conv_w + (size_t)l*1536*4, conv_b + (size_t)l*1536, ucv);
    sgemm_splitk_xp<<<dim3(2,32,XS), 256, 0, stream>>>(ucv, x_proj_w + (size_t)l*XP_N*1536, xpart);
    reduce_xp<<<(ROWS*XP_N)/256, 256, 0, stream>>>(xpart, xp);
    sgemm_tn<<<dim3(24,32), 256, 0, stream>>>(xp, XP_N, dt_proj_w + (size_t)l*1536*48, dt_proj_b + (size_t)l*1536,
                                              delta, ROWS, 1536, 48, 1);
    scan_pass1<<<dim3(6,B_SZ,CH-1), 256, 0, stream>>>(delta, ucv, xp,
                                               A_log + (size_t)l*1536*16, Pend, Hend);
    scan_combine<<<(B_SZ*D_INNER*16)/256, 256, 0, stream>>>(Pend, Hend, Hin);
    scan_pass3<<<dim3(6,B_SZ,CH), 256, 0, stream>>>(delta, ucv, xp, xz,
                                               A_log + (size_t)l*1536*16, D_param + (size_t)l*1536, Hin, ybf);
    // out_proj split-K=4: partials into delta (s=0,1) + ucv (s=2,3), both dead now
    gemm_bf16_sk<<<dim3(6,16,OS), 256, 0, stream>>>(ybf, wbo, delta, ucv, ROWS, 768, 1536);
    reduce_out<<<MN_OUT/256, 256, 0, stream>>>(delta, ucv, hidden);
  }

  add_rmsnorm<<<ROWS, 256, 0, stream>>>(resid, hidden, norm_f_w, normed, nullptr);
  pool_partial<<<dim3(12,16), 256, 0, stream>>>(normed, ppool);
  pool_final<<<12, 256, 0, stream>>>(ppool, pooled);
  cls_head<<<40, 64, 0, stream>>>(pooled, cls_w, cls_b, out);
}

// Round 6
// 826.590 us; speedup vs baseline: 3.9565x; 1.0271x over previous
//
#include <hip/hip_runtime.h>
#include <math.h>

#define D_MODEL 768
#define D_INNER 1536
#define B_SZ 4
#define T_SZ 512
#define ROWS (B_SZ*T_SZ)   // 2048
#define XP_N 80
#define CH 16              // scan chunks
#define CT 32              // T per chunk
#define XS 8               // x_proj split-K factor
#define XKC (D_INNER/XS)   // 192
#define OS 4               // out_proj split-K factor
#define OKC (D_INNER/OS)   // 384
#define MN_OUT (ROWS*768)  // 1572864

typedef __attribute__((ext_vector_type(8))) short bf16x8;
typedef __attribute__((ext_vector_type(4))) float f32x4;

// async global->LDS, 16B per lane, lane-contiguous LDS destination
#define GLL(g, l) __builtin_amdgcn_global_load_lds( \
    (const __attribute__((address_space(1))) void*)(g), \
    (__attribute__((address_space(3))) void*)(l), 16, 0, 0)

__device__ __forceinline__ float sigmoidf_(float x){ return 1.0f/(1.0f+__expf(-x)); }
__device__ __forceinline__ float siluf_(float x){ return x*sigmoidf_(x); }
__device__ __forceinline__ unsigned short f2bf(float f){
  unsigned u = __builtin_bit_cast(unsigned, f);
  u = (u + 0x7FFFu + ((u >> 16) & 1u)) >> 16;   // RNE
  return (unsigned short)u;
}

// ---------------- transpose: x (B,256,512) -> xt (B,512,256) ----------------
__global__ void transpose_x(const float* __restrict__ x, float* __restrict__ xt){
  __shared__ float s[32][33];
  int b = blockIdx.z;
  int t0 = blockIdx.x*32, c0 = blockIdx.y*32;
  int tx = threadIdx.x, ty = threadIdx.y;
  s[ty][tx] = x[((size_t)b*256 + (c0+ty))*512 + (t0+tx)];
  __syncthreads();
  xt[((size_t)b*512 + (t0+ty))*256 + (c0+tx)] = s[tx][ty];
}

// ---------------- bf16 MFMA GEMM w/ global_load_lds staging ----------------
// C[M,N] = A[M,K] * W[N,K]^T.  M%128==0, N%128==0, K%32==0. 256 thr = 4 waves.
// LDS: unpadded 128x32 bf16 tiles (8 KB each). k-chunk (8 elems = 16B) swizzle:
//   LDS(row, khp) holds global chunk khl = (khp - (row>>1)) & 3
// => frag read for (row, quad) at khp = (quad + (row>>1)) & 3 — max 2-way bank alias.
__global__ __launch_bounds__(256) void gemm_bf16(
    const unsigned short* __restrict__ A, const unsigned short* __restrict__ Wb,
    float* __restrict__ C, int M, int N, int K)
{
  __shared__ unsigned short As[128*32];
  __shared__ unsigned short Ws[128*32];
  const int tid = threadIdx.x;
  const int bm = blockIdx.y*128, bn = blockIdx.x*128;
  const int wave = tid >> 6, lane = tid & 63;
  const int wm = (wave >> 1)*64, wn = (wave & 1)*64;
  const int fr = lane & 15, quad = lane >> 4;
  f32x4 acc[4][4] = {};
  // staging decode: instr j of wave covers LDS chunk q16 = j*256 + wave*64 + lane
  const int row0 = (wave*64 + lane) >> 2;        // 0..63 (j=1 adds 64)
  const int khp  = lane & 3;
  const int khl  = (khp + 4 - ((row0 >> 1) & 3)) & 3;   // same for j=1 (row+64)
  const unsigned short* Ag = A  + (size_t)(bm + row0)*K + khl*8;
  const unsigned short* Wg = Wb + (size_t)(bn + row0)*K + khl*8;
  const size_t rstep = (size_t)64*K;
  unsigned short* ldsA = As + wave*512;   // wave-uniform base (bytes: wave*1024)
  unsigned short* ldsW = Ws + wave*512;

  for (int k0 = 0; k0 < K; k0 += 32){
    GLL(Ag + k0,          ldsA);
    GLL(Ag + rstep + k0,  ldsA + 2048);
    GLL(Wg + k0,          ldsW);
    GLL(Wg + rstep + k0,  ldsW + 2048);
    __syncthreads();                     // drains vmcnt: LDS tiles complete
    bf16x8 a[4], b[4];
    #pragma unroll
    for (int i=0;i<4;i++){
      const int row = wm + i*16 + fr;
      a[i] = *(const bf16x8*)(As + row*32 + (((quad + (row>>1)) & 3)*8));
    }
    #pragma unroll
    for (int j=0;j<4;j++){
      const int row = wn + j*16 + fr;
      b[j] = *(const bf16x8*)(Ws + row*32 + (((quad + (row>>1)) & 3)*8));
    }
    #pragma unroll
    for (int i=0;i<4;i++)
      #pragma unroll
      for (int j=0;j<4;j++)
        acc[i][j] = __builtin_amdgcn_mfma_f32_16x16x32_bf16(a[i], b[j], acc[i][j], 0, 0, 0);
    __syncthreads();                     // all frag reads done before overwrite
  }
  // C/D layout: col = lane&15, row = quad*4 + reg  [m89-verified]
  #pragma unroll
  for (int i=0;i<4;i++){
    #pragma unroll
    for (int r=0;r<4;r++){
      const int row = bm + wm + i*16 + quad*4 + r;
      float* Cp = C + (size_t)row*N + bn + wn + fr;
      #pragma unroll
      for (int j=0;j<4;j++)
        Cp[j*16] = acc[i][j][r];
    }
  }
}

// ---------------- bf16 MFMA GEMM, split-K (out_proj partials) ----------------
__global__ __launch_bounds__(256) void gemm_bf16_sk(
    const unsigned short* __restrict__ A, const unsigned short* __restrict__ Wb,
    float* __restrict__ P0, float* __restrict__ P1, int M, int N, int K)
{
  __shared__ unsigned short As[128*32];
  __shared__ unsigned short Ws[128*32];
  const int tid = threadIdx.x;
  const int bm = blockIdx.y*128, bn = blockIdx.x*128;
  const int s = blockIdx.z;
  const int koff = s*OKC;
  const int wave = tid >> 6, lane = tid & 63;
  const int wm = (wave >> 1)*64, wn = (wave & 1)*64;
  const int fr = lane & 15, quad = lane >> 4;
  f32x4 acc[4][4] = {};
  const int row0 = (wave*64 + lane) >> 2;
  const int khp  = lane & 3;
  const int khl  = (khp + 4 - ((row0 >> 1) & 3)) & 3;
  const unsigned short* Ag = A  + (size_t)(bm + row0)*K + koff + khl*8;
  const unsigned short* Wg = Wb + (size_t)(bn + row0)*K + koff + khl*8;
  const size_t rstep = (size_t)64*K;
  unsigned short* ldsA = As + wave*512;
  unsigned short* ldsW = Ws + wave*512;

  for (int k0 = 0; k0 < OKC; k0 += 32){
    GLL(Ag + k0,          ldsA);
    GLL(Ag + rstep + k0,  ldsA + 2048);
    GLL(Wg + k0,          ldsW);
    GLL(Wg + rstep + k0,  ldsW + 2048);
    __syncthreads();
    bf16x8 a[4], b[4];
    #pragma unroll
    for (int i=0;i<4;i++){
      const int row = wm + i*16 + fr;
      a[i] = *(const bf16x8*)(As + row*32 + (((quad + (row>>1)) & 3)*8));
    }
    #pragma unroll
    for (int j=0;j<4;j++){
      const int row = wn + j*16 + fr;
      b[j] = *(const bf16x8*)(Ws + row*32 + (((quad + (row>>1)) & 3)*8));
    }
    #pragma unroll
    for (int i=0;i<4;i++)
      #pragma unroll
      for (int j=0;j<4;j++)
        acc[i][j] = __builtin_amdgcn_mfma_f32_16x16x32_bf16(a[i], b[j], acc[i][j], 0, 0, 0);
    __syncthreads();
  }
  float* Cb = (s < 2 ? P0 : P1) + (size_t)(s & 1)*MN_OUT;
  #pragma unroll
  for (int i=0;i<4;i++){
    #pragma unroll
    for (int r=0;r<4;r++){
      const int row = bm + wm + i*16 + quad*4 + r;
      float* Cp = Cb + (size_t)row*N + bn + wn + fr;
      #pragma unroll
      for (int j=0;j<4;j++)
        Cp[j*16] = acc[i][j][r];
    }
  }
}

// ---------------- fp32 SGEMM (dt_proj / input) ----------------
__global__ __launch_bounds__(256) void sgemm_tn(
    const float* __restrict__ A, int lda,
    const float* __restrict__ W,
    const float* __restrict__ bias,
    float* __restrict__ C, int M, int N, int K, int act)
{
  __shared__ float As[16][64];
  __shared__ float Wsh[16][64];
  const int bm = blockIdx.y*64, bn = blockIdx.x*64;
  const int tid = threadIdx.x;
  const int tx = tid & 15, ty = tid >> 4;
  const int lm = tid & 63, lk = (tid >> 6) << 2;
  float acc[4][4] = {};
  const float* Ap = A + (size_t)(bm+lm)*lda + lk;
  const float* Wp = W + (size_t)(bn+lm)*K + lk;
  const bool wok = (bn+lm) < N;
  for (int k0 = 0; k0 < K; k0 += 16){
    float4 av = *(const float4*)(Ap + k0);
    float4 wv = wok ? *(const float4*)(Wp + k0) : make_float4(0.f,0.f,0.f,0.f);
    As[lk+0][lm]=av.x; As[lk+1][lm]=av.y; As[lk+2][lm]=av.z; As[lk+3][lm]=av.w;
    Wsh[lk+0][lm]=wv.x; Wsh[lk+1][lm]=wv.y; Wsh[lk+2][lm]=wv.z; Wsh[lk+3][lm]=wv.w;
    __syncthreads();
    #pragma unroll
    for (int k = 0; k < 16; k++){
      float a[4], w[4];
      #pragma unroll
      for (int i=0;i<4;i++) a[i] = As[k][ty*4+i];
      #pragma unroll
      for (int j=0;j<4;j++) w[j] = Wsh[k][tx*4+j];
      #pragma unroll
      for (int i=0;i<4;i++)
        #pragma unroll
        for (int j=0;j<4;j++)
          acc[i][j] += a[i]*w[j];
    }
    __syncthreads();
  }
  #pragma unroll
  for (int i=0;i<4;i++){
    const int r = bm + ty*4 + i;
    #pragma unroll
    for (int j=0;j<4;j++){
      const int n = bn + tx*4 + j;
      if (n < N){
        float v = acc[i][j] + (bias ? bias[n] : 0.f);
        if (act == 1){ v = (v > 20.f) ? v : log1pf(__expf(v)); }
        C[(size_t)r*N + n] = v;
      }
    }
  }
}

// ---------------- x_proj split-K fp32 ----------------
__global__ __launch_bounds__(256) void sgemm_splitk_xp(
    const float* __restrict__ A, const float* __restrict__ W,
    float* __restrict__ part)
{
  __shared__ float As[16][64];
  __shared__ float Wsh[16][64];
  const int bm = blockIdx.y*64, bn = blockIdx.x*64;
  const int s = blockIdx.z;
  const int koff = s*XKC;
  const int tid = threadIdx.x;
  const int tx = tid & 15, ty = tid >> 4;
  const int lm = tid & 63, lk = (tid >> 6) << 2;
  float acc[4][4] = {};
  const float* Ap = A + (size_t)(bm+lm)*D_INNER + koff + lk;
  const float* Wp = W + (size_t)(bn+lm)*D_INNER + koff + lk;
  const bool wok = (bn+lm) < XP_N;
  for (int k0 = 0; k0 < XKC; k0 += 16){
    float4 av = *(const float4*)(Ap + k0);
    float4 wv = wok ? *(const float4*)(Wp + k0) : make_float4(0.f,0.f,0.f,0.f);
    As[lk+0][lm]=av.x; As[lk+1][lm]=av.y; As[lk+2][lm]=av.z; As[lk+3][lm]=av.w;
    Wsh[lk+0][lm]=wv.x; Wsh[lk+1][lm]=wv.y; Wsh[lk+2][lm]=wv.z; Wsh[lk+3][lm]=wv.w;
    __syncthreads();
    #pragma unroll
    for (int k = 0; k < 16; k++){
      float a[4], w[4];
      #pragma unroll
      for (int i=0;i<4;i++) a[i] = As[k][ty*4+i];
      #pragma unroll
      for (int j=0;j<4;j++) w[j] = Wsh[k][tx*4+j];
      #pragma unroll
      for (int i=0;i<4;i++)
        #pragma unroll
        for (int j=0;j<4;j++)
          acc[i][j] += a[i]*w[j];
    }
    __syncthreads();
  }
  #pragma unroll
  for (int i=0;i<4;i++){
    const int r = bm + ty*4 + i;
    #pragma unroll
    for (int j=0;j<4;j++){
      const int n = bn + tx*4 + j;
      if (n < XP_N)
        part[((size_t)s*ROWS + r)*XP_N + n] = acc[i][j];
    }
  }
}

__global__ __launch_bounds__(256) void reduce_xp(const float* __restrict__ part,
                                                 float* __restrict__ xp){
  const int i = blockIdx.x*256 + threadIdx.x;
  if (i >= ROWS*XP_N) return;
  float s = 0.f;
  #pragma unroll
  for (int c=0;c<XS;c++) s += part[(size_t)c*ROWS*XP_N + i];
  xp[i] = s;
}

// ---------------- fused: [out_proj partial-reduce +] residual add + RMSNorm [+ weight casts] ----------------
// blocks [0,2048): row work.  resid += sum(partials) (if P0), out = rmsnorm(resid)*w (bf16 or fp32).
// blocks [2048, 2048+cnb1+cnb2): fp32->bf16 weight casts (cin1 -> co1, cin2 -> co2).
__global__ __launch_bounds__(256) void fused_norm_cast(
    float* __restrict__ resid, const float* __restrict__ P0, const float* __restrict__ P1,
    const float* __restrict__ w, unsigned short* __restrict__ obf, float* __restrict__ ofp,
    const float* __restrict__ cin1, unsigned short* __restrict__ co1, int cn1, int cnb1,
    const float* __restrict__ cin2, unsigned short* __restrict__ co2, int cn2)
{
  const int blk = blockIdx.x;
  if (blk >= 2048){
    const int cb = blk - 2048;
    const float* in; unsigned short* o; int i4;
    if (cb < cnb1){ in = cin1; o = co1; i4 = (cb*256 + threadIdx.x)*4; if (i4 >= cn1) return; }
    else { in = cin2; o = co2; i4 = ((cb-cnb1)*256 + threadIdx.x)*4; if (i4 >= cn2) return; }
    float4 v = *(const float4*)(in + i4);
    ushort4 r;
    r.x = f2bf(v.x); r.y = f2bf(v.y); r.z = f2bf(v.z); r.w = f2bf(v.w);
    *(ushort4*)(o + i4) = r;
    return;
  }
  const int row = blk;
  const int tid = threadIdx.x;
  float v[3];
  float ss = 0.f;
  #pragma unroll
  for (int i=0;i<3;i++){
    const int c = tid + i*256;
    const size_t idx = (size_t)row*768 + c;
    float r = resid[idx];
    if (P0) r += (P0[idx] + P0[MN_OUT + idx]) + (P1[idx] + P1[MN_OUT + idx]);
    v[i] = r;
    ss += r*r;
  }
  #pragma unroll
  for (int off=32; off>=1; off>>=1) ss += __shfl_xor(ss, off);
  __shared__ float sred[4];
  const int lane = tid & 63, wv = tid >> 6;
  if (lane == 0) sred[wv] = ss;
  __syncthreads();
  const float tot = sred[0]+sred[1]+sred[2]+sred[3];
  const float scale = rsqrtf(tot*(1.0f/768.0f) + 1e-5f);
  #pragma unroll
  for (int i=0;i<3;i++){
    const int c = tid + i*256;
    const size_t idx = (size_t)row*768 + c;
    if (P0) resid[idx] = v[i];
    const float o = v[i]*scale*w[c];
    if (obf) obf[idx] = f2bf(o);
    else     ofp[idx] = o;
  }
}

// ---------------- causal depthwise conv (K=4) + silu ----------------
__global__ __launch_bounds__(256) void conv_silu(
    const float* __restrict__ xz, const float* __restrict__ cw,
    const float* __restrict__ cb, float* __restrict__ uo)
{
  const int idx = blockIdx.x*256 + threadIdx.x;
  if (idx >= ROWS*D_INNER) return;
  const int d = idx % D_INNER;
  const int row = idx / D_INNER;
  const int t = row & (T_SZ-1);
  float acc = cb[d];
  #pragma unroll
  for (int k=0;k<4;k++){
    const int tt = t - 3 + k;
    if (tt >= 0)
      acc += xz[(size_t)(row - 3 + k)*3072 + d] * cw[d*4 + k];
  }
  uo[idx] = siluf_(acc);
}

// ---------------- chunked selective scan: lane = (b,c,d), 16 n-states in regs ----------------
__global__ __launch_bounds__(256) void scan_pass1(
    const float* __restrict__ delta, const float* __restrict__ u,
    const float* __restrict__ xp, const float* __restrict__ alog,
    float* __restrict__ Pend, float* __restrict__ Hend)
{
  const int d = blockIdx.x*256 + threadIdx.x;
  const int b = blockIdx.y, c = blockIdx.z;
  float4 t0 = *(const float4*)(alog + d*16 + 0);
  float4 t1 = *(const float4*)(alog + d*16 + 4);
  float4 t2 = *(const float4*)(alog + d*16 + 8);
  float4 t3 = *(const float4*)(alog + d*16 + 12);
  float Av[16] = {t0.x,t0.y,t0.z,t0.w,t1.x,t1.y,t1.z,t1.w,
                  t2.x,t2.y,t2.z,t2.w,t3.x,t3.y,t3.z,t3.w};
  float h[16], P[16];
  #pragma unroll
  for (int n=0;n<16;n++){ Av[n] = -__expf(Av[n]); h[n]=0.f; P[n]=1.f; }
  const size_t row0 = (size_t)b*T_SZ + (size_t)c*CT;
  const float* dp = delta + row0*D_INNER + d;
  const float* up = u     + row0*D_INNER + d;
  const float* bp = xp    + row0*XP_N + 48;
  for (int t=0;t<CT;t++){
    const float dv = dp[(size_t)t*D_INNER];
    const float uv = up[(size_t)t*D_INNER];
    const float4 B0 = *(const float4*)(bp + (size_t)t*XP_N);
    const float4 B1 = *(const float4*)(bp + (size_t)t*XP_N + 4);
    const float4 B2 = *(const float4*)(bp + (size_t)t*XP_N + 8);
    const float4 B3 = *(const float4*)(bp + (size_t)t*XP_N + 12);
    const float Bv[16] = {B0.x,B0.y,B0.z,B0.w,B1.x,B1.y,B1.z,B1.w,
                          B2.x,B2.y,B2.z,B2.w,B3.x,B3.y,B3.z,B3.w};
    const float du = dv*uv;
    #pragma unroll
    for (int n=0;n<16;n++){
      const float dA = __expf(dv*Av[n]);
      P[n] *= dA;
      h[n] = dA*h[n] + du*Bv[n];
    }
  }
  float* Pp = Pend + ((size_t)(b*CH+c)*D_INNER + d)*16;
  float* Hp = Hend + ((size_t)(b*CH+c)*D_INNER + d)*16;
  *(float4*)(Pp+ 0) = make_float4(P[0],P[1],P[2],P[3]);
  *(float4*)(Pp+ 4) = make_float4(P[4],P[5],P[6],P[7]);
  *(float4*)(Pp+ 8) = make_float4(P[8],P[9],P[10],P[11]);
  *(float4*)(Pp+12) = make_float4(P[12],P[13],P[14],P[15]);
  *(float4*)(Hp+ 0) = make_float4(h[0],h[1],h[2],h[3]);
  *(float4*)(Hp+ 4) = make_float4(h[4],h[5],h[6],h[7]);
  *(float4*)(Hp+ 8) = make_float4(h[8],h[9],h[10],h[11]);
  *(float4*)(Hp+12) = make_float4(h[12],h[13],h[14],h[15]);
}

__global__ __launch_bounds__(256) void scan_combine(
    const float* __restrict__ Pend, const float* __restrict__ Hend,
    float* __restrict__ Hin)
{
  const int gid = blockIdx.x*256 + threadIdx.x;       // 0..98303
  const int b = gid / (D_INNER*16);
  const int r = gid % (D_INNER*16);
  const size_t base = (size_t)b*CH*D_INNER*16 + r;
  const size_t step = (size_t)D_INNER*16;
  float h = 0.f;
  Hin[base] = 0.f;
  for (int c=0; c<CH-1; c++){
    h = Pend[base + (size_t)c*step]*h + Hend[base + (size_t)c*step];
    Hin[base + (size_t)(c+1)*step] = h;
  }
}

__global__ __launch_bounds__(256) void scan_pass3(
    const float* __restrict__ delta, const float* __restrict__ u,
    const float* __restrict__ xp, const float* __restrict__ xz,
    const float* __restrict__ alog, const float* __restrict__ Dp,
    const float* __restrict__ Hin, unsigned short* __restrict__ yb)
{
  const int d = blockIdx.x*256 + threadIdx.x;
  const int b = blockIdx.y, c = blockIdx.z;
  float4 t0 = *(const float4*)(alog + d*16 + 0);
  float4 t1 = *(const float4*)(alog + d*16 + 4);
  float4 t2 = *(const float4*)(alog + d*16 + 8);
  float4 t3 = *(const float4*)(alog + d*16 + 12);
  float Av[16] = {t0.x,t0.y,t0.z,t0.w,t1.x,t1.y,t1.z,t1.w,
                  t2.x,t2.y,t2.z,t2.w,t3.x,t3.y,t3.z,t3.w};
  #pragma unroll
  for (int n=0;n<16;n++) Av[n] = -__expf(Av[n]);
  const float* Hp = Hin + ((size_t)(b*CH+c)*D_INNER + d)*16;
  float4 h0 = *(const float4*)(Hp+0);
  float4 h1 = *(const float4*)(Hp+4);
  float4 h2 = *(const float4*)(Hp+8);
  float4 h3 = *(const float4*)(Hp+12);
  float h[16] = {h0.x,h0.y,h0.z,h0.w,h1.x,h1.y,h1.z,h1.w,
                 h2.x,h2.y,h2.z,h2.w,h3.x,h3.y,h3.z,h3.w};
  const float Dv = Dp[d];
  const size_t row0 = (size_t)b*T_SZ + (size_t)c*CT;
  const float* dp = delta + row0*D_INNER + d;
  const float* up = u     + row0*D_INNER + d;
  const float* bp = xp    + row0*XP_N + 48;
  const float* cp = xp    + row0*XP_N + 64;
  const float* zp = xz    + row0*3072 + 1536 + d;
  unsigned short* yp = yb + row0*D_INNER + d;
  for (int t=0;t<CT;t++){
    const float dv = dp[(size_t)t*D_INNER];
    const float uv = up[(size_t)t*D_INNER];
    const float zv = zp[(size_t)t*3072];
    const float4 B0 = *(const float4*)(bp + (size_t)t*XP_N);
    const float4 B1 = *(const float4*)(bp + (size_t)t*XP_N + 4);
    const float4 B2 = *(const float4*)(bp + (size_t)t*XP_N + 8);
    const float4 B3 = *(const float4*)(bp + (size_t)t*XP_N + 12);
    const float4 C0 = *(const float4*)(cp + (size_t)t*XP_N);
    const float4 C1 = *(const float4*)(cp + (size_t)t*XP_N + 4);
    const float4 C2 = *(const float4*)(cp + (size_t)t*XP_N + 8);
    const float4 C3 = *(const float4*)(cp + (size_t)t*XP_N + 12);
    const float Bv[16] = {B0.x,B0.y,B0.z,B0.w,B1.x,B1.y,B1.z,B1.w,
                          B2.x,B2.y,B2.z,B2.w,B3.x,B3.y,B3.z,B3.w};
    const float Cv[16] = {C0.x,C0.y,C0.z,C0.w,C1.x,C1.y,C1.z,C1.w,
                          C2.x,C2.y,C2.z,C2.w,C3.x,C3.y,C3.z,C3.w};
    const float du = dv*uv;
    float p = 0.f;
    #pragma unroll
    for (int n=0;n<16;n++){
      const float dA = __expf(dv*Av[n]);
      h[n] = dA*h[n] + du*Bv[n];
      p += h[n]*Cv[n];
    }
    yp[(size_t)t*D_INNER] = f2bf((p + uv*Dv)*siluf_(zv));
  }
}

// ---------------- mean pool stage 1 ----------------
__global__ __launch_bounds__(256) void pool_partial(const float* __restrict__ normed,
                                                    float* __restrict__ part){
  const int i = blockIdx.x*256 + threadIdx.x;    // (b,m) flat, 0..3071
  const int s = blockIdx.y;
  const int b = i / 768, m = i % 768;
  float sum = 0.f;
  const float* p = normed + ((size_t)b*T_SZ + s*32)*768 + m;
  #pragma unroll
  for (int t=0; t<32; t++) sum += p[(size_t)t*768];
  part[s*3072 + i] = sum;
}

// ---------------- fused pool-final + classifier: out (4,10) ----------------
__global__ __launch_bounds__(256) void pool_cls(const float* __restrict__ part,
                                                const float* __restrict__ cw,
                                                const float* __restrict__ cb,
                                                float* __restrict__ out){
  __shared__ float ls[768];
  const int b = blockIdx.x;
  const int tid = threadIdx.x;
  #pragma unroll
  for (int i=0;i<3;i++){
    const int m = tid + i*256;
    float s = 0.f;
    #pragma unroll
    for (int c=0;c<16;c++) s += part[c*3072 + b*768 + m];
    ls[m] = s * (1.0f/T_SZ);
  }
  __syncthreads();
  const int wave = tid >> 6, lane = tid & 63;
  for (int o = wave; o < 10; o += 4){
    float s = 0.f;
    for (int k = lane; k < 768; k += 64) s += ls[k]*cw[o*768 + k];
    #pragma unroll
    for (int off=32; off>=1; off>>=1) s += __shfl_xor(s, off);
    if (lane == 0) out[b*10 + o] = s + cb[o];
  }
}

extern "C" void kernel_launch(void* const* d_in, const int* in_sizes, int n_in,
                              void* d_out, int out_size, void* d_ws, size_t ws_size,
                              hipStream_t stream) {
  const float* x         = (const float*)d_in[0];
  const float* in_proj_w = (const float*)d_in[1];
  const float* conv_w    = (const float*)d_in[2];
  const float* conv_b    = (const float*)d_in[3];
  const float* x_proj_w  = (const float*)d_in[4];
  const float* dt_proj_w = (const float*)d_in[5];
  const float* dt_proj_b = (const float*)d_in[6];
  const float* A_log     = (const float*)d_in[7];
  const float* D_param   = (const float*)d_in[8];
  const float* out_proj_w= (const float*)d_in[9];
  const float* norm_w    = (const float*)d_in[10];
  const float* norm_f_w  = (const float*)d_in[11];
  const float* inp_w     = (const float*)d_in[12];
  const float* inp_b     = (const float*)d_in[13];
  const float* cls_w     = (const float*)d_in[14];
  const float* cls_b     = (const float*)d_in[15];
  float* out = (float*)d_out;

  char* ws = (char*)d_ws;
  auto carve = [&](size_t nelem)->float* {
    float* p = (float*)ws;
    ws += ((nelem*sizeof(float) + 255)/256)*256;
    return p;
  };
  float* xt     = carve((size_t)ROWS*256);
  float* resid  = carve((size_t)ROWS*768);
  float* normed = carve((size_t)ROWS*768);   // bf16 normed (lower) / Pend during scan / fp32 at final
  float* hidden = carve((size_t)ROWS*768);   // Hend during scan (no other use now)
  float* xz     = carve((size_t)ROWS*3072);
  float* ucv    = carve((size_t)ROWS*1536);  // out_proj partials s=2,3 after scan
  float* xp     = carve((size_t)ROWS*XP_N);
  float* delta  = carve((size_t)ROWS*1536);  // out_proj partials s=0,1 after scan
  float* ybf_f  = carve((size_t)ROWS*1536/2);     // bf16 y
  float* wbi_f  = carve((size_t)(3072*768)/2);    // per-layer bf16 in_proj w
  float* wbo_f  = carve((size_t)(768*1536)/2);    // per-layer bf16 out_proj w
  float* Hin    = carve((size_t)B_SZ*CH*D_INNER*16);   // 1.57M floats
  float* xpart  = carve((size_t)XS*ROWS*XP_N);         // 1.31M floats
  float* ppool  = carve((size_t)16*3072);
  float* pooled = carve((size_t)B_SZ*768);
  (void)pooled;

  unsigned short* normedb = (unsigned short*)normed;
  unsigned short* ybf = (unsigned short*)ybf_f;
  unsigned short* wbi = (unsigned short*)wbi_f;
  unsigned short* wbo = (unsigned short*)wbo_f;
  float* Pend = normed;    // dead during scan
  float* Hend = hidden;    // dead during scan

  transpose_x<<<dim3(16,8,4), dim3(32,32), 0, stream>>>(x, xt);
  sgemm_tn<<<dim3(12,32), 256, 0, stream>>>(xt, 256, inp_w, inp_b, resid, ROWS, 768, 256, 0);

  for (int l = 0; l < 4; l++){
    // rows: resid += out_proj partials (l>0), normedb = rmsnorm; casts: layer-l weights -> bf16
    fused_norm_cast<<<2048 + 2304 + 1152, 256, 0, stream>>>(
        resid, l ? delta : nullptr, l ? ucv : nullptr,
        norm_w + (size_t)l*768, normedb, nullptr,
        in_proj_w + (size_t)l*3072*768, wbi, 3072*768, 2304,
        out_proj_w + (size_t)l*768*1536, wbo, 768*1536);
    gemm_bf16<<<dim3(24,16), 256, 0, stream>>>(normedb, wbi, xz, ROWS, 3072, 768);
    conv_silu<<<(ROWS*D_INNER)/256, 256, 0, stream>>>(xz, conv_w + (size_t)l*1536*4, conv_b + (size_t)l*1536, ucv);
    sgemm_splitk_xp<<<dim3(2,32,XS), 256, 0, stream>>>(ucv, x_proj_w + (size_t)l*XP_N*1536, xpart);
    reduce_xp<<<(ROWS*XP_N)/256, 256, 0, stream>>>(xpart, xp);
    sgemm_tn<<<dim3(24,32), 256, 0, stream>>>(xp, XP_N, dt_proj_w + (size_t)l*1536*48, dt_proj_b + (size_t)l*1536,
                                              delta, ROWS, 1536, 48, 1);
    scan_pass1<<<dim3(6,B_SZ,CH-1), 256, 0, stream>>>(delta, ucv, xp,
                                               A_log + (size_t)l*1536*16, Pend, Hend);
    scan_combine<<<(B_SZ*D_INNER*16)/256, 256, 0, stream>>>(Pend, Hend, Hin);
    scan_pass3<<<dim3(6,B_SZ,CH), 256, 0, stream>>>(delta, ucv, xp, xz,
                                               A_log + (size_t)l*1536*16, D_param + (size_t)l*1536, Hin, ybf);
    // out_proj split-K=4: partials into delta (s=0,1) + ucv (s=2,3), both dead now
    gemm_bf16_sk<<<dim3(6,16,OS), 256, 0, stream>>>(ybf, wbo, delta, ucv, ROWS, 768, 1536);
  }

  // final: resid += layer-3 partials, fp32 rmsnorm(norm_f_w) -> normed
  fused_norm_cast<<<2048, 256, 0, stream>>>(
      resid, delta, ucv, norm_f_w, nullptr, normed,
      nullptr, nullptr, 0, 0, nullptr, nullptr, 0);
  pool_partial<<<dim3(12,16), 256, 0, stream>>>(normed, ppool);
  pool_cls<<<4, 256, 0, stream>>>(ppool, cls_w, cls_b, out);
}